// Round 4
// baseline (970.474 us; speedup 1.0000x reference)
//
#include <hip/hip_runtime.h>
#include <cstdint>
#include <cstddef>

#define NN 50000
#define NPAD 50048            // 391 * 128
#define EE 800000
#define ET (EE + NN)
#define GG 64
#define HH 4
#define RSQ 0.9999950000374997f   // 1/sqrt(1+1e-5)

typedef short bf16x8 __attribute__((ext_vector_type(8)));
typedef unsigned short u16x8 __attribute__((ext_vector_type(8)));
typedef float f32x4 __attribute__((ext_vector_type(4)));

__device__ __forceinline__ float bf2f(unsigned short u) {
    union { unsigned int i; float f; } v; v.i = ((unsigned int)u) << 16; return v.f;
}
__device__ __forceinline__ unsigned short f2bf(float f) {
    union { float f; unsigned int i; } v; v.f = f;
    unsigned int u = v.i;
    u += 0x7fffu + ((u >> 16) & 1u);
    return (unsigned short)(u >> 16);
}

static inline void* carve(char*& p, size_t bytes) {
    void* r = (void*)p;
    p += (bytes + 255) & ~(size_t)255;
    return r;
}

// ------------------------------------------------------------- CSR building

__global__ void deg_kernel(const int* __restrict__ dst0, int* __restrict__ deg) {
    int e = blockIdx.x * blockDim.x + threadIdx.x;
    if (e >= EE) return;
    atomicAdd(&deg[dst0[e]], 1);
}

#define SCAN_B 512
__global__ void scan1_kernel(const int* __restrict__ deg, int* __restrict__ out,
                             int* __restrict__ bsum, int n) {
    __shared__ int tmp[SCAN_B];
    int i = blockIdx.x * SCAN_B + threadIdx.x;
    int v = (i < n) ? (deg[i] + 1) : 0;   // +1 self loop
    tmp[threadIdx.x] = v;
    __syncthreads();
    for (int off = 1; off < SCAN_B; off <<= 1) {
        int t = (threadIdx.x >= off) ? tmp[threadIdx.x - off] : 0;
        __syncthreads();
        tmp[threadIdx.x] += t;
        __syncthreads();
    }
    if (i < n) out[i] = tmp[threadIdx.x] - v;       // exclusive
    if (threadIdx.x == SCAN_B - 1) bsum[blockIdx.x] = tmp[threadIdx.x];
}

__global__ void scan2_kernel(int* __restrict__ bsum, int nb) {
    __shared__ int tmp[128];
    int v = (threadIdx.x < nb) ? bsum[threadIdx.x] : 0;
    tmp[threadIdx.x] = v;
    __syncthreads();
    for (int off = 1; off < 128; off <<= 1) {
        int t = (threadIdx.x >= off) ? tmp[threadIdx.x - off] : 0;
        __syncthreads();
        tmp[threadIdx.x] += t;
        __syncthreads();
    }
    if (threadIdx.x < nb) bsum[threadIdx.x] = tmp[threadIdx.x] - v;  // exclusive
}

__global__ void scan3_kernel(int* __restrict__ out, const int* __restrict__ bsum, int n) {
    int i = blockIdx.x * SCAN_B + threadIdx.x;
    if (i < n) out[i] += bsum[blockIdx.x];
}

__global__ void set_total_kernel(int* __restrict__ row_ptr) {
    if (threadIdx.x == 0) row_ptr[NN] = ET;
}

__global__ void fill_edges_kernel(const int* __restrict__ src0, const int* __restrict__ dst0,
                                  const int* __restrict__ row_ptr, int* __restrict__ cursor,
                                  int* __restrict__ ssrc, int* __restrict__ seid,
                                  int* __restrict__ pos) {
    int e = blockIdx.x * blockDim.x + threadIdx.x;
    if (e >= EE) return;
    int d = dst0[e];
    int p = atomicAdd(&cursor[d], 1);
    int idx = row_ptr[d] + p;
    ssrc[idx] = src0[e];
    seid[idx] = e;
    pos[e] = idx;
}

__global__ void fill_loops_kernel(const int* __restrict__ row_ptr, int* __restrict__ cursor,
                                  int* __restrict__ ssrc, int* __restrict__ seid,
                                  int* __restrict__ pos) {
    int n = blockIdx.x * blockDim.x + threadIdx.x;
    if (n >= NN) return;
    int p = atomicAdd(&cursor[n], 1);
    int idx = row_ptr[n] + p;
    ssrc[idx] = n;
    seid[idx] = EE + n;
    pos[EE + n] = idx;
}

// emean via CSR segmented sum — no atomics. Wave per node, lanes over edges.
__global__ __launch_bounds__(256) void emean_csr_kernel(const int* __restrict__ rowptr,
                                                        const int* __restrict__ seid,
                                                        const float* __restrict__ ef,
                                                        float* __restrict__ emean) {
    int wid = (blockIdx.x * blockDim.x + threadIdx.x) >> 6;
    int lane = threadIdx.x & 63;
    if (wid >= NN) return;
    int b = rowptr[wid], e = rowptr[wid + 1];
    float s[6] = {0.f, 0.f, 0.f, 0.f, 0.f, 0.f};
    for (int i = b + lane; i < e; i += 64) {
        int eid = seid[i];
        if (eid < EE) {
            const float* row = &ef[(size_t)eid * 6];
#pragma unroll
            for (int k = 0; k < 6; k++) s[k] += row[k];
        }
    }
#pragma unroll
    for (int off = 32; off; off >>= 1)
#pragma unroll
        for (int k = 0; k < 6; k++) s[k] += __shfl_xor(s[k], off);
    if (lane == 0) {
        float inv = 1.0f / fmaxf((float)(e - b - 1), 1.0f);
#pragma unroll
        for (int k = 0; k < 6; k++) emean[(size_t)wid * 6 + k] = s[k] * inv;
    }
}

// ------------------------------------------------------------- conversions

__global__ void convx_kernel(const float* __restrict__ x, unsigned short* __restrict__ xb) {
    int i = blockIdx.x * blockDim.x + threadIdx.x;
    if (i >= NPAD * 32) return;
    int row = i >> 5;
    float v = 0.f;
    if (row < NN) v = x[i];
    xb[i] = f2bf(v);
}

__global__ void convw_kernel(const float* __restrict__ W, unsigned short* __restrict__ Wt,
                             int K, int Nc) {
    int i = blockIdx.x * blockDim.x + threadIdx.x;
    if (i >= K * Nc) return;
    int c = i / K, k = i - c * K;
    Wt[i] = f2bf(W[(size_t)k * Nc + c]);
}

// ------------------------------------------------------------ bf16 MFMA GEMM
// C[NPAD,Nc] (bf16) = A[NPAD,K] (bf16) @ Bt[Nc,K]^T (bf16), fp32 accumulate.
// 128x128 tile, BK=32, 256 threads = 4 waves (2x2), each wave 64x64 (4x4 frags).

__global__ __launch_bounds__(256) void gemm_bf16_kernel(const unsigned short* __restrict__ A,
                                                        const unsigned short* __restrict__ Bt,
                                                        unsigned short* __restrict__ C,
                                                        int K, int Nc) {
    __shared__ unsigned short As[128][40];
    __shared__ unsigned short Bs[128][40];
    const int tid = threadIdx.x;
    const int bm = blockIdx.x * 128;
    const int bn = blockIdx.y * 128;
    const int lane = tid & 63;
    const int wv = tid >> 6;
    const int wrow = (wv >> 1) * 64;
    const int wcol = (wv & 1) * 64;
    const int lrow = tid >> 1;          // 0..127
    const int lseg = (tid & 1) * 16;    // 0 or 16
    const int l15 = lane & 15;
    const int kgrp = (lane >> 4) * 8;

    f32x4 acc[4][4];
#pragma unroll
    for (int m = 0; m < 4; m++)
#pragma unroll
        for (int n = 0; n < 4; n++) acc[m][n] = (f32x4)0.f;

    for (int k0 = 0; k0 < K; k0 += 32) {
        const unsigned short* ga = &A[(size_t)(bm + lrow) * K + k0 + lseg];
        const unsigned short* gb = &Bt[(size_t)(bn + lrow) * K + k0 + lseg];
        u16x8 a0 = *(const u16x8*)ga;
        u16x8 a1 = *(const u16x8*)(ga + 8);
        u16x8 b0 = *(const u16x8*)gb;
        u16x8 b1 = *(const u16x8*)(gb + 8);
        *(u16x8*)&As[lrow][lseg] = a0;
        *(u16x8*)&As[lrow][lseg + 8] = a1;
        *(u16x8*)&Bs[lrow][lseg] = b0;
        *(u16x8*)&Bs[lrow][lseg + 8] = b1;
        __syncthreads();
        bf16x8 af[4], bfr[4];
#pragma unroll
        for (int m = 0; m < 4; m++)
            af[m] = *(const bf16x8*)&As[wrow + m * 16 + l15][kgrp];
#pragma unroll
        for (int n = 0; n < 4; n++)
            bfr[n] = *(const bf16x8*)&Bs[wcol + n * 16 + l15][kgrp];
#pragma unroll
        for (int m = 0; m < 4; m++)
#pragma unroll
            for (int n = 0; n < 4; n++)
                acc[m][n] = __builtin_amdgcn_mfma_f32_16x16x32_bf16(af[m], bfr[n], acc[m][n], 0, 0, 0);
        __syncthreads();
    }
    // epilogue: D row = (lane>>4)*4 + j, col = lane&15  [m89-verified]
#pragma unroll
    for (int m = 0; m < 4; m++) {
#pragma unroll
        for (int n = 0; n < 4; n++) {
#pragma unroll
            for (int j = 0; j < 4; j++) {
                int row = bm + wrow + m * 16 + (lane >> 4) * 4 + j;
                int col = bn + wcol + n * 16 + l15;
                C[(size_t)row * Nc + col] = f2bf(acc[m][n][j]);
            }
        }
    }
}

// --------------------------------------------------- per-node attention dots

template <int C_>
__global__ __launch_bounds__(256) void attn_node_kernel(const unsigned short* __restrict__ xs,
                                                        const float* __restrict__ a_s,
                                                        const float* __restrict__ a_d,
                                                        float* __restrict__ al_s,
                                                        float* __restrict__ al_d) {
    constexpr int HC = HH * C_;
    constexpr int NK = HC / 64;
    int wid = (blockIdx.x * blockDim.x + threadIdx.x) >> 6;
    int lane = threadIdx.x & 63;
    if (wid >= NN) return;
    const unsigned short* row = xs + (size_t)wid * HC;
    float ss[HH] = {0.f, 0.f, 0.f, 0.f};
    float sd[HH] = {0.f, 0.f, 0.f, 0.f};
#pragma unroll
    for (int k = 0; k < NK; k++) {
        int idx = (k << 6) + lane;
        float v = bf2f(row[idx]);
        float ps = v * a_s[idx];
        float pd = v * a_d[idx];
#pragma unroll
        for (int off = 32; off; off >>= 1) {
            ps += __shfl_xor(ps, off);
            pd += __shfl_xor(pd, off);
        }
        ss[(k * 64) / C_] += ps;
        sd[(k * 64) / C_] += pd;
    }
    if (lane == 0) {
#pragma unroll
        for (int h = 0; h < HH; h++) {
            al_s[(size_t)wid * HH + h] = ss[h];
            al_d[(size_t)wid * HH + h] = sd[h];
        }
    }
}

// ------------------------------------------------------------- edge logits

__global__ void wea_kernel(const float* __restrict__ We, const float* __restrict__ ae,
                           float* __restrict__ Wea, int HC, int C) {
    int t = threadIdx.x;
    if (t >= 24) return;
    int k = t / 4, h = t % 4;
    float s = 0.f;
    for (int c = 0; c < C; c++) s += We[(size_t)k * HC + h * C + c] * ae[(size_t)h * C + c];
    Wea[k * 4 + h] = s;
}

__global__ void edge_al_kernel(const int* __restrict__ src0, const int* __restrict__ dst0,
                               const float* __restrict__ ef, const float* __restrict__ emean,
                               const float* __restrict__ Wea, const int* __restrict__ pos,
                               const float* __restrict__ al_s, const float* __restrict__ al_d,
                               float* __restrict__ al) {
    int e = blockIdx.x * blockDim.x + threadIdx.x;
    if (e >= ET) return;
    int s, d;
    float ev[6];
    if (e < EE) {
        s = src0[e];
        d = dst0[e];
#pragma unroll
        for (int k = 0; k < 6; k++) ev[k] = ef[(size_t)e * 6 + k];
    } else {
        s = d = e - EE;
#pragma unroll
        for (int k = 0; k < 6; k++) ev[k] = emean[(size_t)s * 6 + k];
    }
    float4 as4 = *(const float4*)&al_s[(size_t)s * 4];
    float4 ad4 = *(const float4*)&al_d[(size_t)d * 4];
    float asv[4] = {as4.x, as4.y, as4.z, as4.w};
    float adv[4] = {ad4.x, ad4.y, ad4.z, ad4.w};
    float o[4];
#pragma unroll
    for (int h = 0; h < 4; h++) {
        float v = asv[h] + adv[h];
#pragma unroll
        for (int k = 0; k < 6; k++) v += ev[k] * Wea[k * 4 + h];
        o[h] = v > 0.f ? v : 0.2f * v;
    }
    *(float4*)&al[(size_t)pos[e] * 4] = make_float4(o[0], o[1], o[2], o[3]);
}

// ----------------------- per-dst softmax over CSR-ordered logits (in-place)

__global__ __launch_bounds__(256) void softmax_w_kernel(const int* __restrict__ rowptr,
                                                        float* __restrict__ al) {
    int wid = (blockIdx.x * blockDim.x + threadIdx.x) >> 6;
    int lane = threadIdx.x & 63;
    if (wid >= NN) return;
    int b = rowptr[wid], e = rowptr[wid + 1];
    float m0 = -1e30f, m1 = -1e30f, m2 = -1e30f, m3 = -1e30f;
    for (int i = b + lane; i < e; i += 64) {
        float4 v = *(const float4*)&al[(size_t)i * 4];
        m0 = fmaxf(m0, v.x); m1 = fmaxf(m1, v.y);
        m2 = fmaxf(m2, v.z); m3 = fmaxf(m3, v.w);
    }
#pragma unroll
    for (int off = 32; off; off >>= 1) {
        m0 = fmaxf(m0, __shfl_xor(m0, off)); m1 = fmaxf(m1, __shfl_xor(m1, off));
        m2 = fmaxf(m2, __shfl_xor(m2, off)); m3 = fmaxf(m3, __shfl_xor(m3, off));
    }
    float s0 = 0.f, s1 = 0.f, s2 = 0.f, s3 = 0.f;
    for (int i = b + lane; i < e; i += 64) {
        float4 v = *(const float4*)&al[(size_t)i * 4];
        s0 += __expf(v.x - m0); s1 += __expf(v.y - m1);
        s2 += __expf(v.z - m2); s3 += __expf(v.w - m3);
    }
#pragma unroll
    for (int off = 32; off; off >>= 1) {
        s0 += __shfl_xor(s0, off); s1 += __shfl_xor(s1, off);
        s2 += __shfl_xor(s2, off); s3 += __shfl_xor(s3, off);
    }
    float r0 = 1.f / (s0 + 1e-16f), r1 = 1.f / (s1 + 1e-16f);
    float r2 = 1.f / (s2 + 1e-16f), r3 = 1.f / (s3 + 1e-16f);
    for (int i = b + lane; i < e; i += 64) {
        float4 v = *(const float4*)&al[(size_t)i * 4];
        v.x = __expf(v.x - m0) * r0;
        v.y = __expf(v.y - m1) * r1;
        v.z = __expf(v.z - m2) * r2;
        v.w = __expf(v.w - m3) * r3;
        *(float4*)&al[(size_t)i * 4] = v;
    }
}

// -------------------- aggregation + bias + BN + ELU (wave/node, pure gather)
// lane owns CPL = HC/64 contiguous channels; head = lane>>4 for both configs.

template <int C_>
__global__ __launch_bounds__(256) void aggregate_kernel(const unsigned short* __restrict__ xs,
                                                        const float* __restrict__ w,
                                                        const int* __restrict__ rowptr,
                                                        const int* __restrict__ ssrc,
                                                        const float* __restrict__ bias,
                                                        const float* __restrict__ gam,
                                                        const float* __restrict__ bet,
                                                        unsigned short* __restrict__ hout) {
    constexpr int HC = HH * C_;
    constexpr int CPL = HC / 64;   // 4 (HC=256) or 8 (HC=512)
    int wid = (blockIdx.x * blockDim.x + threadIdx.x) >> 6;
    int lane = threadIdx.x & 63;
    if (wid >= NN) return;
    int b = rowptr[wid], e = rowptr[wid + 1];
    const int h = lane >> 4;

    float acc[CPL];
#pragma unroll
    for (int k = 0; k < CPL; k++) acc[k] = 0.f;

    for (int i = b; i < e; i++) {
        int s = ssrc[i];
        float4 v = *(const float4*)&w[(size_t)i * 4];   // wave-uniform
        float ww = (h == 0) ? v.x : (h == 1) ? v.y : (h == 2) ? v.z : v.w;
        const unsigned short* row = xs + (size_t)s * HC + lane * CPL;
        if constexpr (CPL == 4) {
            uint2 pk = *(const uint2*)row;
            acc[0] += ww * bf2f((unsigned short)(pk.x & 0xffffu));
            acc[1] += ww * bf2f((unsigned short)(pk.x >> 16));
            acc[2] += ww * bf2f((unsigned short)(pk.y & 0xffffu));
            acc[3] += ww * bf2f((unsigned short)(pk.y >> 16));
        } else {
            uint4 pk = *(const uint4*)row;
            acc[0] += ww * bf2f((unsigned short)(pk.x & 0xffffu));
            acc[1] += ww * bf2f((unsigned short)(pk.x >> 16));
            acc[2] += ww * bf2f((unsigned short)(pk.y & 0xffffu));
            acc[3] += ww * bf2f((unsigned short)(pk.y >> 16));
            acc[4] += ww * bf2f((unsigned short)(pk.z & 0xffffu));
            acc[5] += ww * bf2f((unsigned short)(pk.z >> 16));
            acc[6] += ww * bf2f((unsigned short)(pk.w & 0xffffu));
            acc[7] += ww * bf2f((unsigned short)(pk.w >> 16));
        }
    }

    int base = lane * CPL;
    unsigned int opk[CPL / 2];
#pragma unroll
    for (int q = 0; q < CPL / 4; q++) {
        float4 bi = *(const float4*)&bias[base + q * 4];
        float4 ga = *(const float4*)&gam[base + q * 4];
        float4 be = *(const float4*)&bet[base + q * 4];
        float vv[4];
        vv[0] = ga.x * (acc[q * 4 + 0] + bi.x) * RSQ + be.x;
        vv[1] = ga.y * (acc[q * 4 + 1] + bi.y) * RSQ + be.y;
        vv[2] = ga.z * (acc[q * 4 + 2] + bi.z) * RSQ + be.z;
        vv[3] = ga.w * (acc[q * 4 + 3] + bi.w) * RSQ + be.w;
#pragma unroll
        for (int k = 0; k < 4; k++) vv[k] = vv[k] > 0.f ? vv[k] : (__expf(vv[k]) - 1.0f);
        opk[q * 2 + 0] = (unsigned int)f2bf(vv[0]) | ((unsigned int)f2bf(vv[1]) << 16);
        opk[q * 2 + 1] = (unsigned int)f2bf(vv[2]) | ((unsigned int)f2bf(vv[3]) << 16);
    }
    if constexpr (CPL == 4) {
        *(uint2*)&hout[(size_t)wid * HC + base] = make_uint2(opk[0], opk[1]);
    } else {
        *(uint4*)&hout[(size_t)wid * HC + base] = make_uint4(opk[0], opk[1], opk[2], opk[3]);
    }
}

// ----------------------------------------------------------- pooling + head

__global__ void bounds_kernel(const int* __restrict__ batch, int* __restrict__ first,
                              int* __restrict__ last) {
    int n = blockIdx.x * blockDim.x + threadIdx.x;
    if (n >= NN) return;
    int b = batch[n];
    if (n == 0 || batch[n - 1] != b) first[b] = n;
    if (n == NN - 1 || batch[n + 1] != b) last[b] = n;
}

__global__ __launch_bounds__(256) void pool_kernel(const unsigned short* __restrict__ h3,
                                                   const int* __restrict__ batch,
                                                   float* __restrict__ pooled) {
    int c = threadIdx.x;
    int n0 = blockIdx.x * 256;
    int nend = min(n0 + 256, NN);
    float local = 0.f;
    int curg = batch[n0];
    for (int n = n0; n < nend; n++) {
        int g = batch[n];
        if (g != curg) {
            atomicAdd(&pooled[(size_t)curg * 256 + c], local);
            local = 0.f;
            curg = g;
        }
        local += bf2f(h3[(size_t)n * 256 + c]);
    }
    atomicAdd(&pooled[(size_t)curg * 256 + c], local);
}

__global__ void final_kernel(const float* __restrict__ pooled,
                             const int* __restrict__ first, const int* __restrict__ last,
                             const float* __restrict__ Wf1, const float* __restrict__ bf1,
                             const float* __restrict__ gf, const float* __restrict__ bbf,
                             const float* __restrict__ Wf2, const float* __restrict__ bf2,
                             float* __restrict__ out) {
    int g = blockIdx.x;
    int j = threadIdx.x;  // 32 threads
    __shared__ float hh[32];
    float c = fmaxf((float)(last[g] - first[g] + 1), 1.0f);
    float inv = 1.0f / c;
    float acc = bf1[j];
    for (int i = 0; i < 256; i++) acc += (pooled[(size_t)g * 256 + i] * inv) * Wf1[(size_t)i * 32 + j];
    float v = gf[j] * acc * RSQ + bbf[j];
    hh[j] = v > 0.f ? v : (__expf(v) - 1.0f);
    __syncthreads();
    if (j == 0) {
        float l0 = bf2[0], l1 = bf2[1];
        for (int i = 0; i < 32; i++) {
            l0 += hh[i] * Wf2[i * 2 + 0];
            l1 += hh[i] * Wf2[i * 2 + 1];
        }
        float mx = fmaxf(l0, l1);
        float lse = mx + logf(__expf(l0 - mx) + __expf(l1 - mx));
        out[g * 2 + 0] = l0 - lse;
        out[g * 2 + 1] = l1 - lse;
    }
}

// -------------------------------------------------------------------- launch

extern "C" void kernel_launch(void* const* d_in, const int* in_sizes, int n_in,
                              void* d_out, int out_size, void* d_ws, size_t ws_size,
                              hipStream_t stream) {
    (void)in_sizes; (void)n_in; (void)out_size; (void)ws_size;

    const float* x  = (const float*)d_in[0];
    const float* ef = (const float*)d_in[1];
    const float* W_[3]  = {(const float*)d_in[2],  (const float*)d_in[10], (const float*)d_in[18]};
    const float* We_[3] = {(const float*)d_in[3],  (const float*)d_in[11], (const float*)d_in[19]};
    const float* As_[3] = {(const float*)d_in[4],  (const float*)d_in[12], (const float*)d_in[20]};
    const float* Ad_[3] = {(const float*)d_in[5],  (const float*)d_in[13], (const float*)d_in[21]};
    const float* Ae_[3] = {(const float*)d_in[6],  (const float*)d_in[14], (const float*)d_in[22]};
    const float* Bi_[3] = {(const float*)d_in[7],  (const float*)d_in[15], (const float*)d_in[23]};
    const float* Ga_[3] = {(const float*)d_in[8],  (const float*)d_in[16], (const float*)d_in[24]};
    const float* Be_[3] = {(const float*)d_in[9],  (const float*)d_in[17], (const float*)d_in[25]};
    const float* Wf1 = (const float*)d_in[26];
    const float* bf1 = (const float*)d_in[27];
    const float* gf  = (const float*)d_in[28];
    const float* bbf = (const float*)d_in[29];
    const float* Wf2 = (const float*)d_in[30];
    const float* bf2 = (const float*)d_in[31];
    const int* eidx  = (const int*)d_in[32];
    const int* src0  = eidx;
    const int* dst0  = eidx + EE;
    const int* batch = (const int*)d_in[33];
    float* out = (float*)d_out;

    char* p = (char*)d_ws;
    unsigned short* B0 = (unsigned short*)carve(p, (size_t)NPAD * 512 * 2);
    unsigned short* B1 = (unsigned short*)carve(p, (size_t)NPAD * 512 * 2);
    unsigned short* B2 = (unsigned short*)carve(p, (size_t)NPAD * 512 * 2);
    unsigned short* Wt = (unsigned short*)carve(p, (size_t)512 * 512 * 2);
    float* al     = (float*)carve(p, (size_t)ET * 4 * 4);
    float* als    = (float*)carve(p, (size_t)NN * 4 * 4);
    float* ald    = (float*)carve(p, (size_t)NN * 4 * 4);
    float* emean  = (float*)carve(p, (size_t)NN * 6 * 4);
    float* wea    = (float*)carve(p, 256);
    float* pooled = (float*)carve(p, (size_t)GG * 256 * 4);
    int* first  = (int*)carve(p, (size_t)GG * 4);
    int* last   = (int*)carve(p, (size_t)GG * 4);
    int* deg    = (int*)carve(p, (size_t)NN * 4);
    int* rowptr = (int*)carve(p, (size_t)(NN + 1) * 4);
    int* cursor = (int*)carve(p, (size_t)NN * 4);
    int* ssrc   = (int*)carve(p, (size_t)ET * 4);
    int* seid   = (int*)carve(p, (size_t)ET * 4);
    int* pos    = (int*)carve(p, (size_t)ET * 4);
    int* bsum   = (int*)carve(p, 512);

    hipMemsetAsync(deg, 0, (size_t)NN * 4, stream);
    hipMemsetAsync(cursor, 0, (size_t)NN * 4, stream);
    hipMemsetAsync(pooled, 0, (size_t)GG * 256 * 4, stream);
    hipMemsetAsync(first, 0x00, (size_t)GG * 4, stream);
    hipMemsetAsync(last, 0xFF, (size_t)GG * 4, stream);

    deg_kernel<<<(EE + 255) / 256, 256, 0, stream>>>(dst0, deg);

    int nb = (NN + SCAN_B - 1) / SCAN_B;  // 98
    scan1_kernel<<<nb, SCAN_B, 0, stream>>>(deg, rowptr, bsum, NN);
    scan2_kernel<<<1, 128, 0, stream>>>(bsum, nb);
    scan3_kernel<<<nb, SCAN_B, 0, stream>>>(rowptr, bsum, NN);
    set_total_kernel<<<1, 64, 0, stream>>>(rowptr);
    fill_edges_kernel<<<(EE + 255) / 256, 256, 0, stream>>>(src0, dst0, rowptr, cursor,
                                                            ssrc, seid, pos);
    fill_loops_kernel<<<(NN + 255) / 256, 256, 0, stream>>>(rowptr, cursor, ssrc, seid, pos);

    int wblocks = (NN * 64 + 255) / 256;
    emean_csr_kernel<<<wblocks, 256, 0, stream>>>(rowptr, seid, ef, emean);

    convx_kernel<<<(NPAD * 32 + 255) / 256, 256, 0, stream>>>(x, B0);

    const int fin[3] = {32, 256, 512};
    const int HCs[3] = {256, 512, 256};
    const int Cs[3]  = {64, 128, 64};
    const unsigned short* inb[3]  = {B0, B2, B0};
    unsigned short* outb[3]       = {B2, B0, B2};

    for (int li = 0; li < 3; li++) {
        int K = fin[li], HC = HCs[li];
        convw_kernel<<<(K * HC + 255) / 256, 256, 0, stream>>>(W_[li], Wt, K, HC);
        dim3 gg(NPAD / 128, HC / 128);
        gemm_bf16_kernel<<<gg, 256, 0, stream>>>(inb[li], Wt, B1, K, HC);

        if (Cs[li] == 64)
            attn_node_kernel<64><<<wblocks, 256, 0, stream>>>(B1, As_[li], Ad_[li], als, ald);
        else
            attn_node_kernel<128><<<wblocks, 256, 0, stream>>>(B1, As_[li], Ad_[li], als, ald);

        wea_kernel<<<1, 32, 0, stream>>>(We_[li], Ae_[li], wea, HC, Cs[li]);
        edge_al_kernel<<<(ET + 255) / 256, 256, 0, stream>>>(src0, dst0, ef, emean, wea, pos,
                                                             als, ald, al);
        softmax_w_kernel<<<wblocks, 256, 0, stream>>>(rowptr, al);

        if (Cs[li] == 64)
            aggregate_kernel<64><<<wblocks, 256, 0, stream>>>(B1, al, rowptr, ssrc,
                                                              Bi_[li], Ga_[li], Be_[li], outb[li]);
        else
            aggregate_kernel<128><<<wblocks, 256, 0, stream>>>(B1, al, rowptr, ssrc,
                                                               Bi_[li], Ga_[li], Be_[li], outb[li]);
    }

    bounds_kernel<<<(NN + 255) / 256, 256, 0, stream>>>(batch, first, last);
    pool_kernel<<<(NN + 255) / 256, 256, 0, stream>>>(B2, batch, pooled);
    final_kernel<<<GG, 32, 0, stream>>>(pooled, first, last, Wf1, bf1, gf, bbf, Wf2, bf2, out);
}

// Round 5
// 764.204 us; speedup vs baseline: 1.2699x; 1.2699x over previous
//
#include <hip/hip_runtime.h>
#include <cstdint>
#include <cstddef>

#define NN 50000
#define NPAD 50048            // 391 * 128
#define EE 800000
#define ET (EE + NN)
#define GG 64
#define HH 4
#define RSQ 0.9999950000374997f   // 1/sqrt(1+1e-5)

typedef short bf16x8 __attribute__((ext_vector_type(8)));
typedef unsigned short u16x8 __attribute__((ext_vector_type(8)));
typedef float f32x4 __attribute__((ext_vector_type(4)));

__device__ __forceinline__ float bf2f(unsigned short u) {
    union { unsigned int i; float f; } v; v.i = ((unsigned int)u) << 16; return v.f;
}
__device__ __forceinline__ unsigned short f2bf(float f) {
    union { float f; unsigned int i; } v; v.f = f;
    unsigned int u = v.i;
    u += 0x7fffu + ((u >> 16) & 1u);
    return (unsigned short)(u >> 16);
}

static inline void* carve(char*& p, size_t bytes) {
    void* r = (void*)p;
    p += (bytes + 255) & ~(size_t)255;
    return r;
}

// ------------------------------------------------------------- CSR building

__global__ void deg_kernel(const int* __restrict__ dst0, int* __restrict__ deg) {
    int e = blockIdx.x * blockDim.x + threadIdx.x;
    if (e >= EE) return;
    atomicAdd(&deg[dst0[e]], 1);
}

#define SCAN_B 512
__global__ void scan1_kernel(const int* __restrict__ deg, int* __restrict__ out,
                             int* __restrict__ bsum, int n) {
    __shared__ int tmp[SCAN_B];
    int i = blockIdx.x * SCAN_B + threadIdx.x;
    int v = (i < n) ? (deg[i] + 1) : 0;   // +1 self loop
    tmp[threadIdx.x] = v;
    __syncthreads();
    for (int off = 1; off < SCAN_B; off <<= 1) {
        int t = (threadIdx.x >= off) ? tmp[threadIdx.x - off] : 0;
        __syncthreads();
        tmp[threadIdx.x] += t;
        __syncthreads();
    }
    if (i < n) out[i] = tmp[threadIdx.x] - v;       // exclusive
    if (threadIdx.x == SCAN_B - 1) bsum[blockIdx.x] = tmp[threadIdx.x];
}

__global__ void scan2_kernel(int* __restrict__ bsum, int nb) {
    __shared__ int tmp[128];
    int v = (threadIdx.x < nb) ? bsum[threadIdx.x] : 0;
    tmp[threadIdx.x] = v;
    __syncthreads();
    for (int off = 1; off < 128; off <<= 1) {
        int t = (threadIdx.x >= off) ? tmp[threadIdx.x - off] : 0;
        __syncthreads();
        tmp[threadIdx.x] += t;
        __syncthreads();
    }
    if (threadIdx.x < nb) bsum[threadIdx.x] = tmp[threadIdx.x] - v;  // exclusive
}

__global__ void scan3_kernel(int* __restrict__ out, const int* __restrict__ bsum, int n) {
    int i = blockIdx.x * SCAN_B + threadIdx.x;
    if (i < n) out[i] += bsum[blockIdx.x];
}

__global__ void set_total_kernel(int* __restrict__ row_ptr) {
    if (threadIdx.x == 0) row_ptr[NN] = ET;
}

__global__ void fill_edges_kernel(const int* __restrict__ src0, const int* __restrict__ dst0,
                                  const int* __restrict__ row_ptr, int* __restrict__ cursor,
                                  int* __restrict__ ssrc, int* __restrict__ seid) {
    int e = blockIdx.x * blockDim.x + threadIdx.x;
    if (e >= EE) return;
    int d = dst0[e];
    int p = atomicAdd(&cursor[d], 1);
    int idx = row_ptr[d] + p;
    ssrc[idx] = src0[e];
    seid[idx] = e;
}

__global__ void fill_loops_kernel(const int* __restrict__ row_ptr, int* __restrict__ cursor,
                                  int* __restrict__ ssrc, int* __restrict__ seid) {
    int n = blockIdx.x * blockDim.x + threadIdx.x;
    if (n >= NN) return;
    int p = atomicAdd(&cursor[n], 1);
    int idx = row_ptr[n] + p;
    ssrc[idx] = n;
    seid[idx] = EE + n;
}

// emean via CSR segmented sum — no atomics. Wave per node, lanes over edges.
__global__ __launch_bounds__(256) void emean_csr_kernel(const int* __restrict__ rowptr,
                                                        const int* __restrict__ seid,
                                                        const float* __restrict__ ef,
                                                        float* __restrict__ emean) {
    int wid = (blockIdx.x * blockDim.x + threadIdx.x) >> 6;
    int lane = threadIdx.x & 63;
    if (wid >= NN) return;
    int b = rowptr[wid], e = rowptr[wid + 1];
    float s[6] = {0.f, 0.f, 0.f, 0.f, 0.f, 0.f};
    for (int i = b + lane; i < e; i += 64) {
        int eid = seid[i];
        if (eid < EE) {
            const float* row = &ef[(size_t)eid * 6];
#pragma unroll
            for (int k = 0; k < 6; k++) s[k] += row[k];
        }
    }
#pragma unroll
    for (int off = 32; off; off >>= 1)
#pragma unroll
        for (int k = 0; k < 6; k++) s[k] += __shfl_xor(s[k], off);
    if (lane == 0) {
        float inv = 1.0f / fmaxf((float)(e - b - 1), 1.0f);
#pragma unroll
        for (int k = 0; k < 6; k++) emean[(size_t)wid * 6 + k] = s[k] * inv;
    }
}

// ------------------------------------------------------------- conversions

__global__ void convx_kernel(const float* __restrict__ x, unsigned short* __restrict__ xb) {
    int i = blockIdx.x * blockDim.x + threadIdx.x;
    if (i >= NPAD * 32) return;
    int row = i >> 5;
    float v = 0.f;
    if (row < NN) v = x[i];
    xb[i] = f2bf(v);
}

__global__ void convw_kernel(const float* __restrict__ W, unsigned short* __restrict__ Wt,
                             int K, int Nc) {
    int i = blockIdx.x * blockDim.x + threadIdx.x;
    if (i >= K * Nc) return;
    int c = i / K, k = i - c * K;
    Wt[i] = f2bf(W[(size_t)k * Nc + c]);
}

// ------------------------------------------------------------ bf16 MFMA GEMM

__global__ __launch_bounds__(256) void gemm_bf16_kernel(const unsigned short* __restrict__ A,
                                                        const unsigned short* __restrict__ Bt,
                                                        unsigned short* __restrict__ C,
                                                        int K, int Nc) {
    __shared__ unsigned short As[128][40];
    __shared__ unsigned short Bs[128][40];
    const int tid = threadIdx.x;
    const int bm = blockIdx.x * 128;
    const int bn = blockIdx.y * 128;
    const int lane = tid & 63;
    const int wv = tid >> 6;
    const int wrow = (wv >> 1) * 64;
    const int wcol = (wv & 1) * 64;
    const int lrow = tid >> 1;          // 0..127
    const int lseg = (tid & 1) * 16;    // 0 or 16
    const int l15 = lane & 15;
    const int kgrp = (lane >> 4) * 8;

    f32x4 acc[4][4];
#pragma unroll
    for (int m = 0; m < 4; m++)
#pragma unroll
        for (int n = 0; n < 4; n++) acc[m][n] = (f32x4)0.f;

    for (int k0 = 0; k0 < K; k0 += 32) {
        const unsigned short* ga = &A[(size_t)(bm + lrow) * K + k0 + lseg];
        const unsigned short* gb = &Bt[(size_t)(bn + lrow) * K + k0 + lseg];
        u16x8 a0 = *(const u16x8*)ga;
        u16x8 a1 = *(const u16x8*)(ga + 8);
        u16x8 b0 = *(const u16x8*)gb;
        u16x8 b1 = *(const u16x8*)(gb + 8);
        *(u16x8*)&As[lrow][lseg] = a0;
        *(u16x8*)&As[lrow][lseg + 8] = a1;
        *(u16x8*)&Bs[lrow][lseg] = b0;
        *(u16x8*)&Bs[lrow][lseg + 8] = b1;
        __syncthreads();
        bf16x8 af[4], bfr[4];
#pragma unroll
        for (int m = 0; m < 4; m++)
            af[m] = *(const bf16x8*)&As[wrow + m * 16 + l15][kgrp];
#pragma unroll
        for (int n = 0; n < 4; n++)
            bfr[n] = *(const bf16x8*)&Bs[wcol + n * 16 + l15][kgrp];
#pragma unroll
        for (int m = 0; m < 4; m++)
#pragma unroll
            for (int n = 0; n < 4; n++)
                acc[m][n] = __builtin_amdgcn_mfma_f32_16x16x32_bf16(af[m], bfr[n], acc[m][n], 0, 0, 0);
        __syncthreads();
    }
#pragma unroll
    for (int m = 0; m < 4; m++) {
#pragma unroll
        for (int n = 0; n < 4; n++) {
#pragma unroll
            for (int j = 0; j < 4; j++) {
                int row = bm + wrow + m * 16 + (lane >> 4) * 4 + j;
                int col = bn + wcol + n * 16 + l15;
                C[(size_t)row * Nc + col] = f2bf(acc[m][n][j]);
            }
        }
    }
}

// --------------------------------------------------- per-node attention dots

template <int C_>
__global__ __launch_bounds__(256) void attn_node_kernel(const unsigned short* __restrict__ xs,
                                                        const float* __restrict__ a_s,
                                                        const float* __restrict__ a_d,
                                                        float* __restrict__ al_s,
                                                        float* __restrict__ al_d) {
    constexpr int HC = HH * C_;
    constexpr int NK = HC / 64;
    int wid = (blockIdx.x * blockDim.x + threadIdx.x) >> 6;
    int lane = threadIdx.x & 63;
    if (wid >= NN) return;
    const unsigned short* row = xs + (size_t)wid * HC;
    float ss[HH] = {0.f, 0.f, 0.f, 0.f};
    float sd[HH] = {0.f, 0.f, 0.f, 0.f};
#pragma unroll
    for (int k = 0; k < NK; k++) {
        int idx = (k << 6) + lane;
        float v = bf2f(row[idx]);
        float ps = v * a_s[idx];
        float pd = v * a_d[idx];
#pragma unroll
        for (int off = 32; off; off >>= 1) {
            ps += __shfl_xor(ps, off);
            pd += __shfl_xor(pd, off);
        }
        ss[(k * 64) / C_] += ps;
        sd[(k * 64) / C_] += pd;
    }
    if (lane == 0) {
#pragma unroll
        for (int h = 0; h < HH; h++) {
            al_s[(size_t)wid * HH + h] = ss[h];
            al_d[(size_t)wid * HH + h] = sd[h];
        }
    }
}

// ------------------------------------------------------------- edge logits

__global__ void wea_kernel(const float* __restrict__ We, const float* __restrict__ ae,
                           float* __restrict__ Wea, int HC, int C) {
    int t = threadIdx.x;
    if (t >= 24) return;
    int k = t / 4, h = t % 4;
    float s = 0.f;
    for (int c = 0; c < C; c++) s += We[(size_t)k * HC + h * C + c] * ae[(size_t)h * C + c];
    Wea[k * 4 + h] = s;
}

// -------- fused: CSR-ordered edge logits + leaky-relu + per-dst softmax -----
// wave per node; al written coalesced in CSR order, normalized in place.

__global__ __launch_bounds__(256) void logits_softmax_kernel(
        const int* __restrict__ rowptr, const int* __restrict__ ssrc,
        const int* __restrict__ seid, const float* __restrict__ ef,
        const float* __restrict__ emean, const float* __restrict__ Wea,
        const float* __restrict__ als, const float* __restrict__ ald,
        float* __restrict__ al) {
    int wid = (blockIdx.x * blockDim.x + threadIdx.x) >> 6;
    int lane = threadIdx.x & 63;
    if (wid >= NN) return;
    int b = rowptr[wid], e = rowptr[wid + 1];
    float4 ad4 = *(const float4*)&ald[(size_t)wid * 4];   // wave-uniform

    float m0 = -1e30f, m1 = -1e30f, m2 = -1e30f, m3 = -1e30f;
    for (int i = b + lane; i < e; i += 64) {
        int eid = seid[i];
        int s = ssrc[i];
        float4 as4 = *(const float4*)&als[(size_t)s * 4];
        const float* evp = (eid < EE) ? &ef[(size_t)eid * 6] : &emean[(size_t)wid * 6];
        float ev[6];
#pragma unroll
        for (int k = 0; k < 6; k++) ev[k] = evp[k];
        float o[4] = {as4.x + ad4.x, as4.y + ad4.y, as4.z + ad4.z, as4.w + ad4.w};
#pragma unroll
        for (int h = 0; h < 4; h++) {
#pragma unroll
            for (int k = 0; k < 6; k++) o[h] += ev[k] * Wea[k * 4 + h];
            o[h] = o[h] > 0.f ? o[h] : 0.2f * o[h];
        }
        *(float4*)&al[(size_t)i * 4] = make_float4(o[0], o[1], o[2], o[3]);
        m0 = fmaxf(m0, o[0]); m1 = fmaxf(m1, o[1]);
        m2 = fmaxf(m2, o[2]); m3 = fmaxf(m3, o[3]);
    }
#pragma unroll
    for (int off = 32; off; off >>= 1) {
        m0 = fmaxf(m0, __shfl_xor(m0, off)); m1 = fmaxf(m1, __shfl_xor(m1, off));
        m2 = fmaxf(m2, __shfl_xor(m2, off)); m3 = fmaxf(m3, __shfl_xor(m3, off));
    }
    float s0 = 0.f, s1 = 0.f, s2 = 0.f, s3 = 0.f;
    for (int i = b + lane; i < e; i += 64) {
        float4 v = *(const float4*)&al[(size_t)i * 4];
        s0 += __expf(v.x - m0); s1 += __expf(v.y - m1);
        s2 += __expf(v.z - m2); s3 += __expf(v.w - m3);
    }
#pragma unroll
    for (int off = 32; off; off >>= 1) {
        s0 += __shfl_xor(s0, off); s1 += __shfl_xor(s1, off);
        s2 += __shfl_xor(s2, off); s3 += __shfl_xor(s3, off);
    }
    float r0 = 1.f / (s0 + 1e-16f), r1 = 1.f / (s1 + 1e-16f);
    float r2 = 1.f / (s2 + 1e-16f), r3 = 1.f / (s3 + 1e-16f);
    for (int i = b + lane; i < e; i += 64) {
        float4 v = *(const float4*)&al[(size_t)i * 4];
        v.x = __expf(v.x - m0) * r0;
        v.y = __expf(v.y - m1) * r1;
        v.z = __expf(v.z - m2) * r2;
        v.w = __expf(v.w - m3) * r3;
        *(float4*)&al[(size_t)i * 4] = v;
    }
}

// -------- aggregation + bias + BN + ELU (wave/node, pipelined gather) -------
// Window of 64 edges: ssrc/w preloaded coalesced into registers, broadcast by
// __shfl; row gathers unrolled x4 for MLP. OOB edges padded with ww=0.

template <int C_>
__global__ __launch_bounds__(256) void aggregate_kernel(const unsigned short* __restrict__ xs,
                                                        const float* __restrict__ w,
                                                        const int* __restrict__ rowptr,
                                                        const int* __restrict__ ssrc,
                                                        const float* __restrict__ bias,
                                                        const float* __restrict__ gam,
                                                        const float* __restrict__ bet,
                                                        unsigned short* __restrict__ hout) {
    constexpr int HC = HH * C_;
    constexpr int CPL = HC / 64;   // 4 (HC=256) or 8 (HC=512)
    int wid = (blockIdx.x * blockDim.x + threadIdx.x) >> 6;
    int lane = threadIdx.x & 63;
    if (wid >= NN) return;
    int b = rowptr[wid], e = rowptr[wid + 1];
    const int h = lane >> 4;
    const int m15 = lane & 15;

    float acc[CPL];
#pragma unroll
    for (int k = 0; k < CPL; k++) acc[k] = 0.f;

    const unsigned short* xbase = xs + (size_t)lane * CPL;

    for (int base = b; base < e; base += 64) {
        int cnt = e - base; if (cnt > 64) cnt = 64;
        // coalesced preloads
        int spre = (base + lane < e) ? ssrc[base + lane] : wid;
        float wpre[4];
#pragma unroll
        for (int q = 0; q < 4; q++) {
            int idx = base + q * 16 + m15;
            wpre[q] = (idx < e) ? w[(size_t)idx * 4 + h] : 0.f;
        }
        int cnt4 = (cnt + 3) & ~3;
        for (int j = 0; j < cnt4; j += 4) {
            float ww[4];
            if constexpr (CPL == 8) {
                uint4 pk[4];
#pragma unroll
                for (int u = 0; u < 4; u++) {
                    int jj = j + u;
                    int s = __shfl(spre, jj);
                    ww[u] = __shfl(wpre[jj >> 4], (h << 4) | (jj & 15));
                    pk[u] = *(const uint4*)(xbase + (size_t)s * HC);
                }
#pragma unroll
                for (int u = 0; u < 4; u++) {
                    acc[0] += ww[u] * bf2f((unsigned short)(pk[u].x & 0xffffu));
                    acc[1] += ww[u] * bf2f((unsigned short)(pk[u].x >> 16));
                    acc[2] += ww[u] * bf2f((unsigned short)(pk[u].y & 0xffffu));
                    acc[3] += ww[u] * bf2f((unsigned short)(pk[u].y >> 16));
                    acc[4] += ww[u] * bf2f((unsigned short)(pk[u].z & 0xffffu));
                    acc[5] += ww[u] * bf2f((unsigned short)(pk[u].z >> 16));
                    acc[6] += ww[u] * bf2f((unsigned short)(pk[u].w & 0xffffu));
                    acc[7] += ww[u] * bf2f((unsigned short)(pk[u].w >> 16));
                }
            } else {
                uint2 pk[4];
#pragma unroll
                for (int u = 0; u < 4; u++) {
                    int jj = j + u;
                    int s = __shfl(spre, jj);
                    ww[u] = __shfl(wpre[jj >> 4], (h << 4) | (jj & 15));
                    pk[u] = *(const uint2*)(xbase + (size_t)s * HC);
                }
#pragma unroll
                for (int u = 0; u < 4; u++) {
                    acc[0] += ww[u] * bf2f((unsigned short)(pk[u].x & 0xffffu));
                    acc[1] += ww[u] * bf2f((unsigned short)(pk[u].x >> 16));
                    acc[2] += ww[u] * bf2f((unsigned short)(pk[u].y & 0xffffu));
                    acc[3] += ww[u] * bf2f((unsigned short)(pk[u].y >> 16));
                }
            }
        }
    }

    int base_c = lane * CPL;
    unsigned int opk[CPL / 2];
#pragma unroll
    for (int q = 0; q < CPL / 4; q++) {
        float4 bi = *(const float4*)&bias[base_c + q * 4];
        float4 ga = *(const float4*)&gam[base_c + q * 4];
        float4 be = *(const float4*)&bet[base_c + q * 4];
        float vv[4];
        vv[0] = ga.x * (acc[q * 4 + 0] + bi.x) * RSQ + be.x;
        vv[1] = ga.y * (acc[q * 4 + 1] + bi.y) * RSQ + be.y;
        vv[2] = ga.z * (acc[q * 4 + 2] + bi.z) * RSQ + be.z;
        vv[3] = ga.w * (acc[q * 4 + 3] + bi.w) * RSQ + be.w;
#pragma unroll
        for (int k = 0; k < 4; k++) vv[k] = vv[k] > 0.f ? vv[k] : (__expf(vv[k]) - 1.0f);
        opk[q * 2 + 0] = (unsigned int)f2bf(vv[0]) | ((unsigned int)f2bf(vv[1]) << 16);
        opk[q * 2 + 1] = (unsigned int)f2bf(vv[2]) | ((unsigned int)f2bf(vv[3]) << 16);
    }
    if constexpr (CPL == 4) {
        *(uint2*)&hout[(size_t)wid * HC + base_c] = make_uint2(opk[0], opk[1]);
    } else {
        *(uint4*)&hout[(size_t)wid * HC + base_c] = make_uint4(opk[0], opk[1], opk[2], opk[3]);
    }
}

// ----------------------------------------------------------- pooling + head

__global__ void bounds_kernel(const int* __restrict__ batch, int* __restrict__ first,
                              int* __restrict__ last) {
    int n = blockIdx.x * blockDim.x + threadIdx.x;
    if (n >= NN) return;
    int b = batch[n];
    if (n == 0 || batch[n - 1] != b) first[b] = n;
    if (n == NN - 1 || batch[n + 1] != b) last[b] = n;
}

__global__ __launch_bounds__(256) void pool_kernel(const unsigned short* __restrict__ h3,
                                                   const int* __restrict__ batch,
                                                   float* __restrict__ pooled) {
    int c = threadIdx.x;
    int n0 = blockIdx.x * 256;
    int nend = min(n0 + 256, NN);
    float local = 0.f;
    int curg = batch[n0];
    for (int n = n0; n < nend; n++) {
        int g = batch[n];
        if (g != curg) {
            atomicAdd(&pooled[(size_t)curg * 256 + c], local);
            local = 0.f;
            curg = g;
        }
        local += bf2f(h3[(size_t)n * 256 + c]);
    }
    atomicAdd(&pooled[(size_t)curg * 256 + c], local);
}

__global__ void final_kernel(const float* __restrict__ pooled,
                             const int* __restrict__ first, const int* __restrict__ last,
                             const float* __restrict__ Wf1, const float* __restrict__ bf1,
                             const float* __restrict__ gf, const float* __restrict__ bbf,
                             const float* __restrict__ Wf2, const float* __restrict__ bf2,
                             float* __restrict__ out) {
    int g = blockIdx.x;
    int j = threadIdx.x;  // 32 threads
    __shared__ float hh[32];
    float c = fmaxf((float)(last[g] - first[g] + 1), 1.0f);
    float inv = 1.0f / c;
    float acc = bf1[j];
    for (int i = 0; i < 256; i++) acc += (pooled[(size_t)g * 256 + i] * inv) * Wf1[(size_t)i * 32 + j];
    float v = gf[j] * acc * RSQ + bbf[j];
    hh[j] = v > 0.f ? v : (__expf(v) - 1.0f);
    __syncthreads();
    if (j == 0) {
        float l0 = bf2[0], l1 = bf2[1];
        for (int i = 0; i < 32; i++) {
            l0 += hh[i] * Wf2[i * 2 + 0];
            l1 += hh[i] * Wf2[i * 2 + 1];
        }
        float mx = fmaxf(l0, l1);
        float lse = mx + logf(__expf(l0 - mx) + __expf(l1 - mx));
        out[g * 2 + 0] = l0 - lse;
        out[g * 2 + 1] = l1 - lse;
    }
}

// -------------------------------------------------------------------- launch

extern "C" void kernel_launch(void* const* d_in, const int* in_sizes, int n_in,
                              void* d_out, int out_size, void* d_ws, size_t ws_size,
                              hipStream_t stream) {
    (void)in_sizes; (void)n_in; (void)out_size; (void)ws_size;

    const float* x  = (const float*)d_in[0];
    const float* ef = (const float*)d_in[1];
    const float* W_[3]  = {(const float*)d_in[2],  (const float*)d_in[10], (const float*)d_in[18]};
    const float* We_[3] = {(const float*)d_in[3],  (const float*)d_in[11], (const float*)d_in[19]};
    const float* As_[3] = {(const float*)d_in[4],  (const float*)d_in[12], (const float*)d_in[20]};
    const float* Ad_[3] = {(const float*)d_in[5],  (const float*)d_in[13], (const float*)d_in[21]};
    const float* Ae_[3] = {(const float*)d_in[6],  (const float*)d_in[14], (const float*)d_in[22]};
    const float* Bi_[3] = {(const float*)d_in[7],  (const float*)d_in[15], (const float*)d_in[23]};
    const float* Ga_[3] = {(const float*)d_in[8],  (const float*)d_in[16], (const float*)d_in[24]};
    const float* Be_[3] = {(const float*)d_in[9],  (const float*)d_in[17], (const float*)d_in[25]};
    const float* Wf1 = (const float*)d_in[26];
    const float* bf1 = (const float*)d_in[27];
    const float* gf  = (const float*)d_in[28];
    const float* bbf = (const float*)d_in[29];
    const float* Wf2 = (const float*)d_in[30];
    const float* bf2 = (const float*)d_in[31];
    const int* eidx  = (const int*)d_in[32];
    const int* src0  = eidx;
    const int* dst0  = eidx + EE;
    const int* batch = (const int*)d_in[33];
    float* out = (float*)d_out;

    char* p = (char*)d_ws;
    unsigned short* B0 = (unsigned short*)carve(p, (size_t)NPAD * 512 * 2);
    unsigned short* B1 = (unsigned short*)carve(p, (size_t)NPAD * 512 * 2);
    unsigned short* B2 = (unsigned short*)carve(p, (size_t)NPAD * 512 * 2);
    unsigned short* Wt = (unsigned short*)carve(p, (size_t)512 * 512 * 2);
    float* al     = (float*)carve(p, (size_t)ET * 4 * 4);
    float* als    = (float*)carve(p, (size_t)NN * 4 * 4);
    float* ald    = (float*)carve(p, (size_t)NN * 4 * 4);
    float* emean  = (float*)carve(p, (size_t)NN * 6 * 4);
    float* wea    = (float*)carve(p, 256);
    float* pooled = (float*)carve(p, (size_t)GG * 256 * 4);
    int* first  = (int*)carve(p, (size_t)GG * 4);
    int* last   = (int*)carve(p, (size_t)GG * 4);
    int* deg    = (int*)carve(p, (size_t)NN * 4);
    int* rowptr = (int*)carve(p, (size_t)(NN + 1) * 4);
    int* cursor = (int*)carve(p, (size_t)NN * 4);
    int* ssrc   = (int*)carve(p, (size_t)ET * 4);
    int* seid   = (int*)carve(p, (size_t)ET * 4);
    int* bsum   = (int*)carve(p, 512);

    hipMemsetAsync(deg, 0, (size_t)NN * 4, stream);
    hipMemsetAsync(cursor, 0, (size_t)NN * 4, stream);
    hipMemsetAsync(pooled, 0, (size_t)GG * 256 * 4, stream);
    hipMemsetAsync(first, 0x00, (size_t)GG * 4, stream);
    hipMemsetAsync(last, 0xFF, (size_t)GG * 4, stream);

    deg_kernel<<<(EE + 255) / 256, 256, 0, stream>>>(dst0, deg);

    int nb = (NN + SCAN_B - 1) / SCAN_B;  // 98
    scan1_kernel<<<nb, SCAN_B, 0, stream>>>(deg, rowptr, bsum, NN);
    scan2_kernel<<<1, 128, 0, stream>>>(bsum, nb);
    scan3_kernel<<<nb, SCAN_B, 0, stream>>>(rowptr, bsum, NN);
    set_total_kernel<<<1, 64, 0, stream>>>(rowptr);
    fill_edges_kernel<<<(EE + 255) / 256, 256, 0, stream>>>(src0, dst0, rowptr, cursor,
                                                            ssrc, seid);
    fill_loops_kernel<<<(NN + 255) / 256, 256, 0, stream>>>(rowptr, cursor, ssrc, seid);

    int wblocks = (NN * 64 + 255) / 256;
    emean_csr_kernel<<<wblocks, 256, 0, stream>>>(rowptr, seid, ef, emean);

    convx_kernel<<<(NPAD * 32 + 255) / 256, 256, 0, stream>>>(x, B0);

    const int fin[3] = {32, 256, 512};
    const int HCs[3] = {256, 512, 256};
    const int Cs[3]  = {64, 128, 64};
    const unsigned short* inb[3]  = {B0, B2, B0};
    unsigned short* outb[3]       = {B2, B0, B2};

    for (int li = 0; li < 3; li++) {
        int K = fin[li], HC = HCs[li];
        convw_kernel<<<(K * HC + 255) / 256, 256, 0, stream>>>(W_[li], Wt, K, HC);
        dim3 gg(NPAD / 128, HC / 128);
        gemm_bf16_kernel<<<gg, 256, 0, stream>>>(inb[li], Wt, B1, K, HC);

        if (Cs[li] == 64)
            attn_node_kernel<64><<<wblocks, 256, 0, stream>>>(B1, As_[li], Ad_[li], als, ald);
        else
            attn_node_kernel<128><<<wblocks, 256, 0, stream>>>(B1, As_[li], Ad_[li], als, ald);

        wea_kernel<<<1, 32, 0, stream>>>(We_[li], Ae_[li], wea, HC, Cs[li]);
        logits_softmax_kernel<<<wblocks, 256, 0, stream>>>(rowptr, ssrc, seid, ef, emean,
                                                           wea, als, ald, al);

        if (Cs[li] == 64)
            aggregate_kernel<64><<<wblocks, 256, 0, stream>>>(B1, al, rowptr, ssrc,
                                                              Bi_[li], Ga_[li], Be_[li], outb[li]);
        else
            aggregate_kernel<128><<<wblocks, 256, 0, stream>>>(B1, al, rowptr, ssrc,
                                                               Bi_[li], Ga_[li], Be_[li], outb[li]);
    }

    bounds_kernel<<<(NN + 255) / 256, 256, 0, stream>>>(batch, first, last);
    pool_kernel<<<(NN + 255) / 256, 256, 0, stream>>>(B2, batch, pooled);
    final_kernel<<<GG, 32, 0, stream>>>(pooled, first, last, Wf1, bf1, gf, bbf, Wf2, bf2, out);
}

// Round 6
// 683.380 us; speedup vs baseline: 1.4201x; 1.1183x over previous
//
#include <hip/hip_runtime.h>
#include <cstdint>
#include <cstddef>

#define NN 50000
#define NPAD 50048            // 391 * 128
#define EE 800000
#define ET (EE + NN)
#define GG 64
#define HH 4
#define RSQ 0.9999950000374997f   // 1/sqrt(1+1e-5)

typedef short bf16x8 __attribute__((ext_vector_type(8)));
typedef unsigned short u16x8 __attribute__((ext_vector_type(8)));
typedef float f32x4 __attribute__((ext_vector_type(4)));
typedef float f32x2 __attribute__((ext_vector_type(2)));

__device__ __forceinline__ float bf2f(unsigned short u) {
    union { unsigned int i; float f; } v; v.i = ((unsigned int)u) << 16; return v.f;
}
__device__ __forceinline__ unsigned short f2bf(float f) {
    union { float f; unsigned int i; } v; v.f = f;
    unsigned int u = v.i;
    u += 0x7fffu + ((u >> 16) & 1u);
    return (unsigned short)(u >> 16);
}

// ---------------------------------------------------------------- fp8 e4m3

#if __has_builtin(__builtin_amdgcn_cvt_pk_fp8_f32) && __has_builtin(__builtin_amdgcn_cvt_pk_f32_fp8)
#define FP8_HW 1
#else
#define FP8_HW 0
#endif

#if !FP8_HW
__device__ __forceinline__ unsigned int enc1_fp8(float f) {
    unsigned int u = __float_as_uint(f);
    unsigned int s = (u >> 24) & 0x80u;
    float a = fabsf(f);
    a = fminf(a, 448.f);
    unsigned int b;
    if (a >= 0.015625f) {
        unsigned int ub = __float_as_uint(a);
        unsigned int mant = ub & 0x7FFFFFu;
        unsigned int keep = mant >> 20;
        unsigned int rem = mant & 0xFFFFFu;
        unsigned int exp = (ub >> 23) - 127u + 7u;
        unsigned int q = (exp << 3) | keep;
        if (rem > 0x80000u || (rem == 0x80000u && (q & 1u))) q++;
        if (q > 0x7Eu) q = 0x7Eu;
        b = q;
    } else {
        int q = (int)(a * 512.0f + 0.5f);
        b = (q > 7) ? 0x08u : (unsigned int)q;
    }
    return s | b;
}
__device__ __forceinline__ float dec1_fp8(unsigned int b) {
    unsigned int sgn = (b & 0x80u) << 24;
    float r;
    if (b & 0x78u) {
        r = __uint_as_float(sgn | (((b & 0x7Fu) + 0x3C0u) << 20));
    } else {
        r = (float)(b & 7u) * 0x1p-9f;
        r = (b & 0x80u) ? -r : r;
    }
    return r;
}
#endif

__device__ __forceinline__ unsigned int pk4_fp8(float f0, float f1, float f2, float f3) {
#if FP8_HW
    int r = __builtin_amdgcn_cvt_pk_fp8_f32(f0, f1, 0, false);
    r = __builtin_amdgcn_cvt_pk_fp8_f32(f2, f3, r, true);
    return (unsigned int)r;
#else
    return enc1_fp8(f0) | (enc1_fp8(f1) << 8) | (enc1_fp8(f2) << 16) | (enc1_fp8(f3) << 24);
#endif
}

__device__ __forceinline__ void dec4_fp8(unsigned int u, float* f) {
#if FP8_HW
    f32x2 lo = __builtin_amdgcn_cvt_pk_f32_fp8((int)u, false);
    f32x2 hi = __builtin_amdgcn_cvt_pk_f32_fp8((int)u, true);
    f[0] = lo[0]; f[1] = lo[1]; f[2] = hi[0]; f[3] = hi[1];
#else
    f[0] = dec1_fp8(u & 0xFFu);
    f[1] = dec1_fp8((u >> 8) & 0xFFu);
    f[2] = dec1_fp8((u >> 16) & 0xFFu);
    f[3] = dec1_fp8(u >> 24);
#endif
}

static inline void* carve(char*& p, size_t bytes) {
    void* r = (void*)p;
    p += (bytes + 255) & ~(size_t)255;
    return r;
}

// ------------------------------------------------------------- CSR building

__global__ void deg_kernel(const int* __restrict__ dst0, int* __restrict__ deg) {
    int e = blockIdx.x * blockDim.x + threadIdx.x;
    if (e >= EE) return;
    atomicAdd(&deg[dst0[e]], 1);
}

#define SCAN_B 512
__global__ void scan1_kernel(const int* __restrict__ deg, int* __restrict__ out,
                             int* __restrict__ bsum, int n) {
    __shared__ int tmp[SCAN_B];
    int i = blockIdx.x * SCAN_B + threadIdx.x;
    int v = (i < n) ? (deg[i] + 1) : 0;   // +1 self loop
    tmp[threadIdx.x] = v;
    __syncthreads();
    for (int off = 1; off < SCAN_B; off <<= 1) {
        int t = (threadIdx.x >= off) ? tmp[threadIdx.x - off] : 0;
        __syncthreads();
        tmp[threadIdx.x] += t;
        __syncthreads();
    }
    if (i < n) out[i] = tmp[threadIdx.x] - v;       // exclusive
    if (threadIdx.x == SCAN_B - 1) bsum[blockIdx.x] = tmp[threadIdx.x];
}

__global__ void scan2_kernel(int* __restrict__ bsum, int nb) {
    __shared__ int tmp[128];
    int v = (threadIdx.x < nb) ? bsum[threadIdx.x] : 0;
    tmp[threadIdx.x] = v;
    __syncthreads();
    for (int off = 1; off < 128; off <<= 1) {
        int t = (threadIdx.x >= off) ? tmp[threadIdx.x - off] : 0;
        __syncthreads();
        tmp[threadIdx.x] += t;
        __syncthreads();
    }
    if (threadIdx.x < nb) bsum[threadIdx.x] = tmp[threadIdx.x] - v;  // exclusive
}

__global__ void scan3_kernel(int* __restrict__ out, const int* __restrict__ bsum, int n) {
    int i = blockIdx.x * SCAN_B + threadIdx.x;
    if (i < n) out[i] += bsum[blockIdx.x];
}

__global__ void set_total_kernel(int* __restrict__ row_ptr) {
    if (threadIdx.x == 0) row_ptr[NN] = ET;
}

__global__ void fill_edges_kernel(const int* __restrict__ src0, const int* __restrict__ dst0,
                                  const int* __restrict__ row_ptr, int* __restrict__ cursor,
                                  int* __restrict__ ssrc, int* __restrict__ seid) {
    int e = blockIdx.x * blockDim.x + threadIdx.x;
    if (e >= EE) return;
    int d = dst0[e];
    int p = atomicAdd(&cursor[d], 1);
    int idx = row_ptr[d] + p;
    ssrc[idx] = src0[e];
    seid[idx] = e;
}

__global__ void fill_loops_kernel(const int* __restrict__ row_ptr, int* __restrict__ cursor,
                                  int* __restrict__ ssrc, int* __restrict__ seid) {
    int n = blockIdx.x * blockDim.x + threadIdx.x;
    if (n >= NN) return;
    int p = atomicAdd(&cursor[n], 1);
    int idx = row_ptr[n] + p;
    ssrc[idx] = n;
    seid[idx] = EE + n;
}

// emean via CSR segmented sum — no atomics. Wave per node, lanes over edges.
__global__ __launch_bounds__(256) void emean_csr_kernel(const int* __restrict__ rowptr,
                                                        const int* __restrict__ seid,
                                                        const float* __restrict__ ef,
                                                        float* __restrict__ emean) {
    int wid = (blockIdx.x * blockDim.x + threadIdx.x) >> 6;
    int lane = threadIdx.x & 63;
    if (wid >= NN) return;
    int b = rowptr[wid], e = rowptr[wid + 1];
    float s[6] = {0.f, 0.f, 0.f, 0.f, 0.f, 0.f};
    for (int i = b + lane; i < e; i += 64) {
        int eid = seid[i];
        if (eid < EE) {
            const float* row = &ef[(size_t)eid * 6];
#pragma unroll
            for (int k = 0; k < 6; k++) s[k] += row[k];
        }
    }
#pragma unroll
    for (int off = 32; off; off >>= 1)
#pragma unroll
        for (int k = 0; k < 6; k++) s[k] += __shfl_xor(s[k], off);
    if (lane == 0) {
        float inv = 1.0f / fmaxf((float)(e - b - 1), 1.0f);
#pragma unroll
        for (int k = 0; k < 6; k++) emean[(size_t)wid * 6 + k] = s[k] * inv;
    }
}

// ------------------------------------------------------------- conversions

__global__ void convx_kernel(const float* __restrict__ x, unsigned short* __restrict__ xb) {
    int i = blockIdx.x * blockDim.x + threadIdx.x;
    if (i >= NPAD * 32) return;
    int row = i >> 5;
    float v = 0.f;
    if (row < NN) v = x[i];
    xb[i] = f2bf(v);
}

__global__ void convw_kernel(const float* __restrict__ W, unsigned short* __restrict__ Wt,
                             int K, int Nc) {
    int i = blockIdx.x * blockDim.x + threadIdx.x;
    if (i >= K * Nc) return;
    int c = i / K, k = i - c * K;
    Wt[i] = f2bf(W[(size_t)k * Nc + c]);
}

// bf16 -> fp8 mirror for the gather path; 8 elements per thread.
__global__ __launch_bounds__(256) void conv8_kernel(const unsigned short* __restrict__ in,
                                                    uint2* __restrict__ out8, int total8) {
    int i = blockIdx.x * blockDim.x + threadIdx.x;
    if (i >= total8) return;
    u16x8 v = *(const u16x8*)&in[(size_t)i * 8];
    unsigned int r0 = pk4_fp8(bf2f(v[0]), bf2f(v[1]), bf2f(v[2]), bf2f(v[3]));
    unsigned int r1 = pk4_fp8(bf2f(v[4]), bf2f(v[5]), bf2f(v[6]), bf2f(v[7]));
    out8[i] = make_uint2(r0, r1);
}

// ------------------------------------------------------------ bf16 MFMA GEMM

__global__ __launch_bounds__(256) void gemm_bf16_kernel(const unsigned short* __restrict__ A,
                                                        const unsigned short* __restrict__ Bt,
                                                        unsigned short* __restrict__ C,
                                                        int K, int Nc) {
    __shared__ unsigned short As[128][40];
    __shared__ unsigned short Bs[128][40];
    const int tid = threadIdx.x;
    const int bm = blockIdx.x * 128;
    const int bn = blockIdx.y * 128;
    const int lane = tid & 63;
    const int wv = tid >> 6;
    const int wrow = (wv >> 1) * 64;
    const int wcol = (wv & 1) * 64;
    const int lrow = tid >> 1;          // 0..127
    const int lseg = (tid & 1) * 16;    // 0 or 16
    const int l15 = lane & 15;
    const int kgrp = (lane >> 4) * 8;

    f32x4 acc[4][4];
#pragma unroll
    for (int m = 0; m < 4; m++)
#pragma unroll
        for (int n = 0; n < 4; n++) acc[m][n] = (f32x4)0.f;

    for (int k0 = 0; k0 < K; k0 += 32) {
        const unsigned short* ga = &A[(size_t)(bm + lrow) * K + k0 + lseg];
        const unsigned short* gb = &Bt[(size_t)(bn + lrow) * K + k0 + lseg];
        u16x8 a0 = *(const u16x8*)ga;
        u16x8 a1 = *(const u16x8*)(ga + 8);
        u16x8 b0 = *(const u16x8*)gb;
        u16x8 b1 = *(const u16x8*)(gb + 8);
        *(u16x8*)&As[lrow][lseg] = a0;
        *(u16x8*)&As[lrow][lseg + 8] = a1;
        *(u16x8*)&Bs[lrow][lseg] = b0;
        *(u16x8*)&Bs[lrow][lseg + 8] = b1;
        __syncthreads();
        bf16x8 af[4], bfr[4];
#pragma unroll
        for (int m = 0; m < 4; m++)
            af[m] = *(const bf16x8*)&As[wrow + m * 16 + l15][kgrp];
#pragma unroll
        for (int n = 0; n < 4; n++)
            bfr[n] = *(const bf16x8*)&Bs[wcol + n * 16 + l15][kgrp];
#pragma unroll
        for (int m = 0; m < 4; m++)
#pragma unroll
            for (int n = 0; n < 4; n++)
                acc[m][n] = __builtin_amdgcn_mfma_f32_16x16x32_bf16(af[m], bfr[n], acc[m][n], 0, 0, 0);
        __syncthreads();
    }
#pragma unroll
    for (int m = 0; m < 4; m++) {
#pragma unroll
        for (int n = 0; n < 4; n++) {
#pragma unroll
            for (int j = 0; j < 4; j++) {
                int row = bm + wrow + m * 16 + (lane >> 4) * 4 + j;
                int col = bn + wcol + n * 16 + l15;
                C[(size_t)row * Nc + col] = f2bf(acc[m][n][j]);
            }
        }
    }
}

// --------------------------------------------------- per-node attention dots

template <int C_>
__global__ __launch_bounds__(256) void attn_node_kernel(const unsigned short* __restrict__ xs,
                                                        const float* __restrict__ a_s,
                                                        const float* __restrict__ a_d,
                                                        float* __restrict__ al_s,
                                                        float* __restrict__ al_d) {
    constexpr int HC = HH * C_;
    constexpr int NK = HC / 64;
    int wid = (blockIdx.x * blockDim.x + threadIdx.x) >> 6;
    int lane = threadIdx.x & 63;
    if (wid >= NN) return;
    const unsigned short* row = xs + (size_t)wid * HC;
    float ss[HH] = {0.f, 0.f, 0.f, 0.f};
    float sd[HH] = {0.f, 0.f, 0.f, 0.f};
#pragma unroll
    for (int k = 0; k < NK; k++) {
        int idx = (k << 6) + lane;
        float v = bf2f(row[idx]);
        float ps = v * a_s[idx];
        float pd = v * a_d[idx];
#pragma unroll
        for (int off = 32; off; off >>= 1) {
            ps += __shfl_xor(ps, off);
            pd += __shfl_xor(pd, off);
        }
        ss[(k * 64) / C_] += ps;
        sd[(k * 64) / C_] += pd;
    }
    if (lane == 0) {
#pragma unroll
        for (int h = 0; h < HH; h++) {
            al_s[(size_t)wid * HH + h] = ss[h];
            al_d[(size_t)wid * HH + h] = sd[h];
        }
    }
}

// ------------------------------------------------------------- edge logits

__global__ void wea_kernel(const float* __restrict__ We, const float* __restrict__ ae,
                           float* __restrict__ Wea, int HC, int C) {
    int t = threadIdx.x;
    if (t >= 24) return;
    int k = t / 4, h = t % 4;
    float s = 0.f;
    for (int c = 0; c < C; c++) s += We[(size_t)k * HC + h * C + c] * ae[(size_t)h * C + c];
    Wea[k * 4 + h] = s;
}

// -------- fused: CSR-ordered edge logits + leaky-relu + per-dst softmax -----

__global__ __launch_bounds__(256) void logits_softmax_kernel(
        const int* __restrict__ rowptr, const int* __restrict__ ssrc,
        const int* __restrict__ seid, const float* __restrict__ ef,
        const float* __restrict__ emean, const float* __restrict__ Wea,
        const float* __restrict__ als, const float* __restrict__ ald,
        float* __restrict__ al) {
    int wid = (blockIdx.x * blockDim.x + threadIdx.x) >> 6;
    int lane = threadIdx.x & 63;
    if (wid >= NN) return;
    int b = rowptr[wid], e = rowptr[wid + 1];
    float4 ad4 = *(const float4*)&ald[(size_t)wid * 4];   // wave-uniform

    float m0 = -1e30f, m1 = -1e30f, m2 = -1e30f, m3 = -1e30f;
    for (int i = b + lane; i < e; i += 64) {
        int eid = seid[i];
        int s = ssrc[i];
        float4 as4 = *(const float4*)&als[(size_t)s * 4];
        const float* evp = (eid < EE) ? &ef[(size_t)eid * 6] : &emean[(size_t)wid * 6];
        float ev[6];
#pragma unroll
        for (int k = 0; k < 6; k++) ev[k] = evp[k];
        float o[4] = {as4.x + ad4.x, as4.y + ad4.y, as4.z + ad4.z, as4.w + ad4.w};
#pragma unroll
        for (int h = 0; h < 4; h++) {
#pragma unroll
            for (int k = 0; k < 6; k++) o[h] += ev[k] * Wea[k * 4 + h];
            o[h] = o[h] > 0.f ? o[h] : 0.2f * o[h];
        }
        *(float4*)&al[(size_t)i * 4] = make_float4(o[0], o[1], o[2], o[3]);
        m0 = fmaxf(m0, o[0]); m1 = fmaxf(m1, o[1]);
        m2 = fmaxf(m2, o[2]); m3 = fmaxf(m3, o[3]);
    }
#pragma unroll
    for (int off = 32; off; off >>= 1) {
        m0 = fmaxf(m0, __shfl_xor(m0, off)); m1 = fmaxf(m1, __shfl_xor(m1, off));
        m2 = fmaxf(m2, __shfl_xor(m2, off)); m3 = fmaxf(m3, __shfl_xor(m3, off));
    }
    float s0 = 0.f, s1 = 0.f, s2 = 0.f, s3 = 0.f;
    for (int i = b + lane; i < e; i += 64) {
        float4 v = *(const float4*)&al[(size_t)i * 4];
        s0 += __expf(v.x - m0); s1 += __expf(v.y - m1);
        s2 += __expf(v.z - m2); s3 += __expf(v.w - m3);
    }
#pragma unroll
    for (int off = 32; off; off >>= 1) {
        s0 += __shfl_xor(s0, off); s1 += __shfl_xor(s1, off);
        s2 += __shfl_xor(s2, off); s3 += __shfl_xor(s3, off);
    }
    float r0 = 1.f / (s0 + 1e-16f), r1 = 1.f / (s1 + 1e-16f);
    float r2 = 1.f / (s2 + 1e-16f), r3 = 1.f / (s3 + 1e-16f);
    for (int i = b + lane; i < e; i += 64) {
        float4 v = *(const float4*)&al[(size_t)i * 4];
        v.x = __expf(v.x - m0) * r0;
        v.y = __expf(v.y - m1) * r1;
        v.z = __expf(v.z - m2) * r2;
        v.w = __expf(v.w - m3) * r3;
        *(float4*)&al[(size_t)i * 4] = v;
    }
}

// ----- aggregation + bias + BN + ELU (wave/node, fp8 gather, 8-deep MLP) ----

template <int C_>
__global__ __launch_bounds__(256) void aggregate_kernel(const unsigned char* __restrict__ xs8,
                                                        const float* __restrict__ w,
                                                        const int* __restrict__ rowptr,
                                                        const int* __restrict__ ssrc,
                                                        const float* __restrict__ bias,
                                                        const float* __restrict__ gam,
                                                        const float* __restrict__ bet,
                                                        unsigned short* __restrict__ hout) {
    constexpr int HC = HH * C_;
    constexpr int CPL = HC / 64;   // bytes/lane: 4 (HC=256) or 8 (HC=512)
    int wid = (blockIdx.x * blockDim.x + threadIdx.x) >> 6;
    int lane = threadIdx.x & 63;
    if (wid >= NN) return;
    int b = rowptr[wid], e = rowptr[wid + 1];
    const int h = lane >> 4;
    const int m15 = lane & 15;

    float acc[CPL];
#pragma unroll
    for (int k = 0; k < CPL; k++) acc[k] = 0.f;

    const unsigned char* xbase = xs8 + (size_t)lane * CPL;

    for (int base = b; base < e; base += 64) {
        int cnt = e - base; if (cnt > 64) cnt = 64;
        int spre = (base + lane < e) ? ssrc[base + lane] : wid;
        float wpre[4];
#pragma unroll
        for (int q = 0; q < 4; q++) {
            int idx = base + q * 16 + m15;
            wpre[q] = (idx < e) ? w[(size_t)idx * 4 + h] : 0.f;
        }
        int cnt8 = (cnt + 7) & ~7;
        for (int j = 0; j < cnt8; j += 8) {
            float ww[8];
            if constexpr (CPL == 8) {
                uint2 pk[8];
#pragma unroll
                for (int u = 0; u < 8; u++) {
                    int jj = j + u;
                    int s = __shfl(spre, jj);
                    ww[u] = __shfl(wpre[jj >> 4], (h << 4) | (jj & 15));
                    pk[u] = *(const uint2*)(xbase + (size_t)s * HC);
                }
#pragma unroll
                for (int u = 0; u < 8; u++) {
                    float f[4];
                    dec4_fp8(pk[u].x, f);
                    acc[0] += ww[u] * f[0]; acc[1] += ww[u] * f[1];
                    acc[2] += ww[u] * f[2]; acc[3] += ww[u] * f[3];
                    dec4_fp8(pk[u].y, f);
                    acc[4] += ww[u] * f[0]; acc[5] += ww[u] * f[1];
                    acc[6] += ww[u] * f[2]; acc[7] += ww[u] * f[3];
                }
            } else {
                unsigned int pk[8];
#pragma unroll
                for (int u = 0; u < 8; u++) {
                    int jj = j + u;
                    int s = __shfl(spre, jj);
                    ww[u] = __shfl(wpre[jj >> 4], (h << 4) | (jj & 15));
                    pk[u] = *(const unsigned int*)(xbase + (size_t)s * HC);
                }
#pragma unroll
                for (int u = 0; u < 8; u++) {
                    float f[4];
                    dec4_fp8(pk[u], f);
                    acc[0] += ww[u] * f[0]; acc[1] += ww[u] * f[1];
                    acc[2] += ww[u] * f[2]; acc[3] += ww[u] * f[3];
                }
            }
        }
    }

    int base_c = lane * CPL;
    unsigned int opk[CPL / 2];
#pragma unroll
    for (int q = 0; q < CPL / 4; q++) {
        float4 bi = *(const float4*)&bias[base_c + q * 4];
        float4 ga = *(const float4*)&gam[base_c + q * 4];
        float4 be = *(const float4*)&bet[base_c + q * 4];
        float vv[4];
        vv[0] = ga.x * (acc[q * 4 + 0] + bi.x) * RSQ + be.x;
        vv[1] = ga.y * (acc[q * 4 + 1] + bi.y) * RSQ + be.y;
        vv[2] = ga.z * (acc[q * 4 + 2] + bi.z) * RSQ + be.z;
        vv[3] = ga.w * (acc[q * 4 + 3] + bi.w) * RSQ + be.w;
#pragma unroll
        for (int k = 0; k < 4; k++) vv[k] = vv[k] > 0.f ? vv[k] : (__expf(vv[k]) - 1.0f);
        opk[q * 2 + 0] = (unsigned int)f2bf(vv[0]) | ((unsigned int)f2bf(vv[1]) << 16);
        opk[q * 2 + 1] = (unsigned int)f2bf(vv[2]) | ((unsigned int)f2bf(vv[3]) << 16);
    }
    if constexpr (CPL == 4) {
        *(uint2*)&hout[(size_t)wid * HC + base_c] = make_uint2(opk[0], opk[1]);
    } else {
        *(uint4*)&hout[(size_t)wid * HC + base_c] = make_uint4(opk[0], opk[1], opk[2], opk[3]);
    }
}

// ----------------------------------------------------------- pooling + head

__global__ void bounds_kernel(const int* __restrict__ batch, int* __restrict__ first,
                              int* __restrict__ last) {
    int n = blockIdx.x * blockDim.x + threadIdx.x;
    if (n >= NN) return;
    int b = batch[n];
    if (n == 0 || batch[n - 1] != b) first[b] = n;
    if (n == NN - 1 || batch[n + 1] != b) last[b] = n;
}

__global__ __launch_bounds__(256) void pool_kernel(const unsigned short* __restrict__ h3,
                                                   const int* __restrict__ batch,
                                                   float* __restrict__ pooled) {
    int c = threadIdx.x;
    int n0 = blockIdx.x * 256;
    int nend = min(n0 + 256, NN);
    float local = 0.f;
    int curg = batch[n0];
    for (int n = n0; n < nend; n++) {
        int g = batch[n];
        if (g != curg) {
            atomicAdd(&pooled[(size_t)curg * 256 + c], local);
            local = 0.f;
            curg = g;
        }
        local += bf2f(h3[(size_t)n * 256 + c]);
    }
    atomicAdd(&pooled[(size_t)curg * 256 + c], local);
}

__global__ void final_kernel(const float* __restrict__ pooled,
                             const int* __restrict__ first, const int* __restrict__ last,
                             const float* __restrict__ Wf1, const float* __restrict__ bf1,
                             const float* __restrict__ gf, const float* __restrict__ bbf,
                             const float* __restrict__ Wf2, const float* __restrict__ bf2,
                             float* __restrict__ out) {
    int g = blockIdx.x;
    int j = threadIdx.x;  // 32 threads
    __shared__ float hh[32];
    float c = fmaxf((float)(last[g] - first[g] + 1), 1.0f);
    float inv = 1.0f / c;
    float acc = bf1[j];
    for (int i = 0; i < 256; i++) acc += (pooled[(size_t)g * 256 + i] * inv) * Wf1[(size_t)i * 32 + j];
    float v = gf[j] * acc * RSQ + bbf[j];
    hh[j] = v > 0.f ? v : (__expf(v) - 1.0f);
    __syncthreads();
    if (j == 0) {
        float l0 = bf2[0], l1 = bf2[1];
        for (int i = 0; i < 32; i++) {
            l0 += hh[i] * Wf2[i * 2 + 0];
            l1 += hh[i] * Wf2[i * 2 + 1];
        }
        float mx = fmaxf(l0, l1);
        float lse = mx + logf(__expf(l0 - mx) + __expf(l1 - mx));
        out[g * 2 + 0] = l0 - lse;
        out[g * 2 + 1] = l1 - lse;
    }
}

// -------------------------------------------------------------------- launch

extern "C" void kernel_launch(void* const* d_in, const int* in_sizes, int n_in,
                              void* d_out, int out_size, void* d_ws, size_t ws_size,
                              hipStream_t stream) {
    (void)in_sizes; (void)n_in; (void)out_size; (void)ws_size;

    const float* x  = (const float*)d_in[0];
    const float* ef = (const float*)d_in[1];
    const float* W_[3]  = {(const float*)d_in[2],  (const float*)d_in[10], (const float*)d_in[18]};
    const float* We_[3] = {(const float*)d_in[3],  (const float*)d_in[11], (const float*)d_in[19]};
    const float* As_[3] = {(const float*)d_in[4],  (const float*)d_in[12], (const float*)d_in[20]};
    const float* Ad_[3] = {(const float*)d_in[5],  (const float*)d_in[13], (const float*)d_in[21]};
    const float* Ae_[3] = {(const float*)d_in[6],  (const float*)d_in[14], (const float*)d_in[22]};
    const float* Bi_[3] = {(const float*)d_in[7],  (const float*)d_in[15], (const float*)d_in[23]};
    const float* Ga_[3] = {(const float*)d_in[8],  (const float*)d_in[16], (const float*)d_in[24]};
    const float* Be_[3] = {(const float*)d_in[9],  (const float*)d_in[17], (const float*)d_in[25]};
    const float* Wf1 = (const float*)d_in[26];
    const float* bf1 = (const float*)d_in[27];
    const float* gf  = (const float*)d_in[28];
    const float* bbf = (const float*)d_in[29];
    const float* Wf2 = (const float*)d_in[30];
    const float* bf2 = (const float*)d_in[31];
    const int* eidx  = (const int*)d_in[32];
    const int* src0  = eidx;
    const int* dst0  = eidx + EE;
    const int* batch = (const int*)d_in[33];
    float* out = (float*)d_out;

    char* p = (char*)d_ws;
    unsigned short* B0 = (unsigned short*)carve(p, (size_t)NPAD * 512 * 2);
    unsigned short* B1 = (unsigned short*)carve(p, (size_t)NPAD * 512 * 2);
    unsigned short* B2 = (unsigned short*)carve(p, (size_t)NPAD * 512 * 2);
    unsigned char*  X8 = (unsigned char*)carve(p, (size_t)NPAD * 512);
    unsigned short* Wt = (unsigned short*)carve(p, (size_t)512 * 512 * 2);
    float* al     = (float*)carve(p, (size_t)ET * 4 * 4);
    float* als    = (float*)carve(p, (size_t)NN * 4 * 4);
    float* ald    = (float*)carve(p, (size_t)NN * 4 * 4);
    float* emean  = (float*)carve(p, (size_t)NN * 6 * 4);
    float* wea    = (float*)carve(p, 256);
    float* pooled = (float*)carve(p, (size_t)GG * 256 * 4);
    int* first  = (int*)carve(p, (size_t)GG * 4);
    int* last   = (int*)carve(p, (size_t)GG * 4);
    int* deg    = (int*)carve(p, (size_t)NN * 4);
    int* rowptr = (int*)carve(p, (size_t)(NN + 1) * 4);
    int* cursor = (int*)carve(p, (size_t)NN * 4);
    int* ssrc   = (int*)carve(p, (size_t)ET * 4);
    int* seid   = (int*)carve(p, (size_t)ET * 4);
    int* bsum   = (int*)carve(p, 512);

    hipMemsetAsync(deg, 0, (size_t)NN * 4, stream);
    hipMemsetAsync(cursor, 0, (size_t)NN * 4, stream);
    hipMemsetAsync(pooled, 0, (size_t)GG * 256 * 4, stream);
    hipMemsetAsync(first, 0x00, (size_t)GG * 4, stream);
    hipMemsetAsync(last, 0xFF, (size_t)GG * 4, stream);

    deg_kernel<<<(EE + 255) / 256, 256, 0, stream>>>(dst0, deg);

    int nb = (NN + SCAN_B - 1) / SCAN_B;  // 98
    scan1_kernel<<<nb, SCAN_B, 0, stream>>>(deg, rowptr, bsum, NN);
    scan2_kernel<<<1, 128, 0, stream>>>(bsum, nb);
    scan3_kernel<<<nb, SCAN_B, 0, stream>>>(rowptr, bsum, NN);
    set_total_kernel<<<1, 64, 0, stream>>>(rowptr);
    fill_edges_kernel<<<(EE + 255) / 256, 256, 0, stream>>>(src0, dst0, rowptr, cursor,
                                                            ssrc, seid);
    fill_loops_kernel<<<(NN + 255) / 256, 256, 0, stream>>>(rowptr, cursor, ssrc, seid);

    int wblocks = (NN * 64 + 255) / 256;
    emean_csr_kernel<<<wblocks, 256, 0, stream>>>(rowptr, seid, ef, emean);

    convx_kernel<<<(NPAD * 32 + 255) / 256, 256, 0, stream>>>(x, B0);

    const int fin[3] = {32, 256, 512};
    const int HCs[3] = {256, 512, 256};
    const int Cs[3]  = {64, 128, 64};
    const unsigned short* inb[3]  = {B0, B2, B0};
    unsigned short* outb[3]       = {B2, B0, B2};

    for (int li = 0; li < 3; li++) {
        int K = fin[li], HC = HCs[li];
        convw_kernel<<<(K * HC + 255) / 256, 256, 0, stream>>>(W_[li], Wt, K, HC);
        dim3 gg(NPAD / 128, HC / 128);
        gemm_bf16_kernel<<<gg, 256, 0, stream>>>(inb[li], Wt, B1, K, HC);

        int total8 = NPAD * HC / 8;
        conv8_kernel<<<(total8 + 255) / 256, 256, 0, stream>>>(B1, (uint2*)X8, total8);

        if (Cs[li] == 64)
            attn_node_kernel<64><<<wblocks, 256, 0, stream>>>(B1, As_[li], Ad_[li], als, ald);
        else
            attn_node_kernel<128><<<wblocks, 256, 0, stream>>>(B1, As_[li], Ad_[li], als, ald);

        wea_kernel<<<1, 32, 0, stream>>>(We_[li], Ae_[li], wea, HC, Cs[li]);
        logits_softmax_kernel<<<wblocks, 256, 0, stream>>>(rowptr, ssrc, seid, ef, emean,
                                                           wea, als, ald, al);

        if (Cs[li] == 64)
            aggregate_kernel<64><<<wblocks, 256, 0, stream>>>(X8, al, rowptr, ssrc,
                                                              Bi_[li], Ga_[li], Be_[li], outb[li]);
        else
            aggregate_kernel<128><<<wblocks, 256, 0, stream>>>(X8, al, rowptr, ssrc,
                                                               Bi_[li], Ga_[li], Be_[li], outb[li]);
    }

    bounds_kernel<<<(NN + 255) / 256, 256, 0, stream>>>(batch, first, last);
    pool_kernel<<<(NN + 255) / 256, 256, 0, stream>>>(B2, batch, pooled);
    final_kernel<<<GG, 32, 0, stream>>>(pooled, first, last, Wf1, bf1, gf, bbf, Wf2, bf2, out);
}

// Round 7
// 635.883 us; speedup vs baseline: 1.5262x; 1.0747x over previous
//
#include <hip/hip_runtime.h>
#include <cstdint>
#include <cstddef>

#define NN 50000
#define NPAD 50048            // 391 * 128
#define EE 800000
#define ET (EE + NN)
#define GG 64
#define HH 4
#define RSQ 0.9999950000374997f   // 1/sqrt(1+1e-5)

typedef short bf16x8 __attribute__((ext_vector_type(8)));
typedef unsigned short u16x8 __attribute__((ext_vector_type(8)));
typedef float f32x4 __attribute__((ext_vector_type(4)));
typedef float f32x2 __attribute__((ext_vector_type(2)));

__device__ __forceinline__ float bf2f(unsigned short u) {
    union { unsigned int i; float f; } v; v.i = ((unsigned int)u) << 16; return v.f;
}
__device__ __forceinline__ unsigned short f2bf(float f) {
    union { float f; unsigned int i; } v; v.f = f;
    unsigned int u = v.i;
    u += 0x7fffu + ((u >> 16) & 1u);
    return (unsigned short)(u >> 16);
}

// ---------------------------------------------------------------- fp8 e4m3

#if __has_builtin(__builtin_amdgcn_cvt_pk_fp8_f32) && __has_builtin(__builtin_amdgcn_cvt_pk_f32_fp8)
#define FP8_HW 1
#else
#define FP8_HW 0
#endif

#if !FP8_HW
__device__ __forceinline__ unsigned int enc1_fp8(float f) {
    unsigned int u = __float_as_uint(f);
    unsigned int s = (u >> 24) & 0x80u;
    float a = fabsf(f);
    a = fminf(a, 448.f);
    unsigned int b;
    if (a >= 0.015625f) {
        unsigned int ub = __float_as_uint(a);
        unsigned int mant = ub & 0x7FFFFFu;
        unsigned int keep = mant >> 20;
        unsigned int rem = mant & 0xFFFFFu;
        unsigned int exp = (ub >> 23) - 127u + 7u;
        unsigned int q = (exp << 3) | keep;
        if (rem > 0x80000u || (rem == 0x80000u && (q & 1u))) q++;
        if (q > 0x7Eu) q = 0x7Eu;
        b = q;
    } else {
        int q = (int)(a * 512.0f + 0.5f);
        b = (q > 7) ? 0x08u : (unsigned int)q;
    }
    return s | b;
}
__device__ __forceinline__ float dec1_fp8(unsigned int b) {
    unsigned int sgn = (b & 0x80u) << 24;
    float r;
    if (b & 0x78u) {
        r = __uint_as_float(sgn | (((b & 0x7Fu) + 0x3C0u) << 20));
    } else {
        r = (float)(b & 7u) * 0x1p-9f;
        r = (b & 0x80u) ? -r : r;
    }
    return r;
}
#endif

__device__ __forceinline__ unsigned int pk4_fp8(float f0, float f1, float f2, float f3) {
#if FP8_HW
    int r = __builtin_amdgcn_cvt_pk_fp8_f32(f0, f1, 0, false);
    r = __builtin_amdgcn_cvt_pk_fp8_f32(f2, f3, r, true);
    return (unsigned int)r;
#else
    return enc1_fp8(f0) | (enc1_fp8(f1) << 8) | (enc1_fp8(f2) << 16) | (enc1_fp8(f3) << 24);
#endif
}

__device__ __forceinline__ void dec4_fp8(unsigned int u, float* f) {
#if FP8_HW
    f32x2 lo = __builtin_amdgcn_cvt_pk_f32_fp8((int)u, false);
    f32x2 hi = __builtin_amdgcn_cvt_pk_f32_fp8((int)u, true);
    f[0] = lo[0]; f[1] = lo[1]; f[2] = hi[0]; f[3] = hi[1];
#else
    f[0] = dec1_fp8(u & 0xFFu);
    f[1] = dec1_fp8((u >> 8) & 0xFFu);
    f[2] = dec1_fp8((u >> 16) & 0xFFu);
    f[3] = dec1_fp8(u >> 24);
#endif
}

static inline void* carve(char*& p, size_t bytes) {
    void* r = (void*)p;
    p += (bytes + 255) & ~(size_t)255;
    return r;
}

// ------------------------------------------------------------- CSR building

__global__ void deg_kernel(const int* __restrict__ dst0, int* __restrict__ deg) {
    int e = blockIdx.x * blockDim.x + threadIdx.x;
    if (e >= EE) return;
    atomicAdd(&deg[dst0[e]], 1);
}

#define SCAN_B 512
__global__ void scan1_kernel(const int* __restrict__ deg, int* __restrict__ out,
                             int* __restrict__ bsum, int n) {
    __shared__ int tmp[SCAN_B];
    int i = blockIdx.x * SCAN_B + threadIdx.x;
    int v = (i < n) ? (deg[i] + 1) : 0;   // +1 self loop
    tmp[threadIdx.x] = v;
    __syncthreads();
    for (int off = 1; off < SCAN_B; off <<= 1) {
        int t = (threadIdx.x >= off) ? tmp[threadIdx.x - off] : 0;
        __syncthreads();
        tmp[threadIdx.x] += t;
        __syncthreads();
    }
    if (i < n) out[i] = tmp[threadIdx.x] - v;       // exclusive
    if (threadIdx.x == SCAN_B - 1) bsum[blockIdx.x] = tmp[threadIdx.x];
}

__global__ void scan2_kernel(int* __restrict__ bsum, int nb) {
    __shared__ int tmp[128];
    int v = (threadIdx.x < nb) ? bsum[threadIdx.x] : 0;
    tmp[threadIdx.x] = v;
    __syncthreads();
    for (int off = 1; off < 128; off <<= 1) {
        int t = (threadIdx.x >= off) ? tmp[threadIdx.x - off] : 0;
        __syncthreads();
        tmp[threadIdx.x] += t;
        __syncthreads();
    }
    if (threadIdx.x < nb) bsum[threadIdx.x] = tmp[threadIdx.x] - v;  // exclusive
}

__global__ void scan3_kernel(int* __restrict__ out, const int* __restrict__ bsum, int n) {
    int i = blockIdx.x * SCAN_B + threadIdx.x;
    if (i < n) out[i] += bsum[blockIdx.x];
}

__global__ void set_total_kernel(int* __restrict__ row_ptr) {
    if (threadIdx.x == 0) row_ptr[NN] = ET;
}

__global__ void fill_edges_kernel(const int* __restrict__ src0, const int* __restrict__ dst0,
                                  const int* __restrict__ row_ptr, int* __restrict__ cursor,
                                  int* __restrict__ ssrc, int* __restrict__ seid) {
    int e = blockIdx.x * blockDim.x + threadIdx.x;
    if (e >= EE) return;
    int d = dst0[e];
    int p = atomicAdd(&cursor[d], 1);
    int idx = row_ptr[d] + p;
    ssrc[idx] = src0[e];
    seid[idx] = e;
}

__global__ void fill_loops_kernel(const int* __restrict__ row_ptr, int* __restrict__ cursor,
                                  int* __restrict__ ssrc, int* __restrict__ seid) {
    int n = blockIdx.x * blockDim.x + threadIdx.x;
    if (n >= NN) return;
    int p = atomicAdd(&cursor[n], 1);
    int idx = row_ptr[n] + p;
    ssrc[idx] = n;
    seid[idx] = EE + n;
}

// emean via CSR segmented sum — no atomics. Wave per node, lanes over edges.
__global__ __launch_bounds__(256) void emean_csr_kernel(const int* __restrict__ rowptr,
                                                        const int* __restrict__ seid,
                                                        const float* __restrict__ ef,
                                                        float* __restrict__ emean) {
    int wid = (blockIdx.x * blockDim.x + threadIdx.x) >> 6;
    int lane = threadIdx.x & 63;
    if (wid >= NN) return;
    int b = rowptr[wid], e = rowptr[wid + 1];
    float s[6] = {0.f, 0.f, 0.f, 0.f, 0.f, 0.f};
    for (int i = b + lane; i < e; i += 64) {
        int eid = seid[i];
        if (eid < EE) {
            const float* row = &ef[(size_t)eid * 6];
#pragma unroll
            for (int k = 0; k < 6; k++) s[k] += row[k];
        }
    }
#pragma unroll
    for (int off = 32; off; off >>= 1)
#pragma unroll
        for (int k = 0; k < 6; k++) s[k] += __shfl_xor(s[k], off);
    if (lane == 0) {
        float inv = 1.0f / fmaxf((float)(e - b - 1), 1.0f);
#pragma unroll
        for (int k = 0; k < 6; k++) emean[(size_t)wid * 6 + k] = s[k] * inv;
    }
}

// ------------------------------------------------------------- conversions

__global__ void convx_kernel(const float* __restrict__ x, unsigned short* __restrict__ xb) {
    int i = blockIdx.x * blockDim.x + threadIdx.x;
    if (i >= NPAD * 32) return;
    int row = i >> 5;
    float v = 0.f;
    if (row < NN) v = x[i];
    xb[i] = f2bf(v);
}

__global__ void convw_kernel(const float* __restrict__ W, unsigned short* __restrict__ Wt,
                             int K, int Nc) {
    int i = blockIdx.x * blockDim.x + threadIdx.x;
    if (i >= K * Nc) return;
    int c = i / K, k = i - c * K;
    Wt[i] = f2bf(W[(size_t)k * Nc + c]);
}

// bf16 -> fp8 mirror for the gather path; 8 elements per thread.
__global__ __launch_bounds__(256) void conv8_kernel(const unsigned short* __restrict__ in,
                                                    uint2* __restrict__ out8, int total8) {
    int i = blockIdx.x * blockDim.x + threadIdx.x;
    if (i >= total8) return;
    u16x8 v = *(const u16x8*)&in[(size_t)i * 8];
    unsigned int r0 = pk4_fp8(bf2f(v[0]), bf2f(v[1]), bf2f(v[2]), bf2f(v[3]));
    unsigned int r1 = pk4_fp8(bf2f(v[4]), bf2f(v[5]), bf2f(v[6]), bf2f(v[7]));
    out8[i] = make_uint2(r0, r1);
}

// ------------------------------------------------------------ bf16 MFMA GEMM

__global__ __launch_bounds__(256) void gemm_bf16_kernel(const unsigned short* __restrict__ A,
                                                        const unsigned short* __restrict__ Bt,
                                                        unsigned short* __restrict__ C,
                                                        int K, int Nc) {
    __shared__ unsigned short As[128][40];
    __shared__ unsigned short Bs[128][40];
    const int tid = threadIdx.x;
    const int bm = blockIdx.x * 128;
    const int bn = blockIdx.y * 128;
    const int lane = tid & 63;
    const int wv = tid >> 6;
    const int wrow = (wv >> 1) * 64;
    const int wcol = (wv & 1) * 64;
    const int lrow = tid >> 1;          // 0..127
    const int lseg = (tid & 1) * 16;    // 0 or 16
    const int l15 = lane & 15;
    const int kgrp = (lane >> 4) * 8;

    f32x4 acc[4][4];
#pragma unroll
    for (int m = 0; m < 4; m++)
#pragma unroll
        for (int n = 0; n < 4; n++) acc[m][n] = (f32x4)0.f;

    for (int k0 = 0; k0 < K; k0 += 32) {
        const unsigned short* ga = &A[(size_t)(bm + lrow) * K + k0 + lseg];
        const unsigned short* gb = &Bt[(size_t)(bn + lrow) * K + k0 + lseg];
        u16x8 a0 = *(const u16x8*)ga;
        u16x8 a1 = *(const u16x8*)(ga + 8);
        u16x8 b0 = *(const u16x8*)gb;
        u16x8 b1 = *(const u16x8*)(gb + 8);
        *(u16x8*)&As[lrow][lseg] = a0;
        *(u16x8*)&As[lrow][lseg + 8] = a1;
        *(u16x8*)&Bs[lrow][lseg] = b0;
        *(u16x8*)&Bs[lrow][lseg + 8] = b1;
        __syncthreads();
        bf16x8 af[4], bfr[4];
#pragma unroll
        for (int m = 0; m < 4; m++)
            af[m] = *(const bf16x8*)&As[wrow + m * 16 + l15][kgrp];
#pragma unroll
        for (int n = 0; n < 4; n++)
            bfr[n] = *(const bf16x8*)&Bs[wcol + n * 16 + l15][kgrp];
#pragma unroll
        for (int m = 0; m < 4; m++)
#pragma unroll
            for (int n = 0; n < 4; n++)
                acc[m][n] = __builtin_amdgcn_mfma_f32_16x16x32_bf16(af[m], bfr[n], acc[m][n], 0, 0, 0);
        __syncthreads();
    }
#pragma unroll
    for (int m = 0; m < 4; m++) {
#pragma unroll
        for (int n = 0; n < 4; n++) {
#pragma unroll
            for (int j = 0; j < 4; j++) {
                int row = bm + wrow + m * 16 + (lane >> 4) * 4 + j;
                int col = bn + wcol + n * 16 + l15;
                C[(size_t)row * Nc + col] = f2bf(acc[m][n][j]);
            }
        }
    }
}

// --------------------------------------------------- per-node attention dots

template <int C_>
__global__ __launch_bounds__(256) void attn_node_kernel(const unsigned short* __restrict__ xs,
                                                        const float* __restrict__ a_s,
                                                        const float* __restrict__ a_d,
                                                        float* __restrict__ al_s,
                                                        float* __restrict__ al_d) {
    constexpr int HC = HH * C_;
    constexpr int NK = HC / 64;
    int wid = (blockIdx.x * blockDim.x + threadIdx.x) >> 6;
    int lane = threadIdx.x & 63;
    if (wid >= NN) return;
    const unsigned short* row = xs + (size_t)wid * HC;
    float ss[HH] = {0.f, 0.f, 0.f, 0.f};
    float sd[HH] = {0.f, 0.f, 0.f, 0.f};
#pragma unroll
    for (int k = 0; k < NK; k++) {
        int idx = (k << 6) + lane;
        float v = bf2f(row[idx]);
        float ps = v * a_s[idx];
        float pd = v * a_d[idx];
#pragma unroll
        for (int off = 32; off; off >>= 1) {
            ps += __shfl_xor(ps, off);
            pd += __shfl_xor(pd, off);
        }
        ss[(k * 64) / C_] += ps;
        sd[(k * 64) / C_] += pd;
    }
    if (lane == 0) {
#pragma unroll
        for (int h = 0; h < HH; h++) {
            al_s[(size_t)wid * HH + h] = ss[h];
            al_d[(size_t)wid * HH + h] = sd[h];
        }
    }
}

// ------------------------------------------------------------- edge logits

__global__ void wea_kernel(const float* __restrict__ We, const float* __restrict__ ae,
                           float* __restrict__ Wea, int HC, int C) {
    int t = threadIdx.x;
    if (t >= 24) return;
    int k = t / 4, h = t % 4;
    float s = 0.f;
    for (int c = 0; c < C; c++) s += We[(size_t)k * HC + h * C + c] * ae[(size_t)h * C + c];
    Wea[k * 4 + h] = s;
}

// -------- fused: CSR-ordered edge logits + leaky-relu + per-dst softmax -----

__global__ __launch_bounds__(256) void logits_softmax_kernel(
        const int* __restrict__ rowptr, const int* __restrict__ ssrc,
        const int* __restrict__ seid, const float* __restrict__ ef,
        const float* __restrict__ emean, const float* __restrict__ Wea,
        const float* __restrict__ als, const float* __restrict__ ald,
        float* __restrict__ al) {
    int wid = (blockIdx.x * blockDim.x + threadIdx.x) >> 6;
    int lane = threadIdx.x & 63;
    if (wid >= NN) return;
    int b = rowptr[wid], e = rowptr[wid + 1];
    float4 ad4 = *(const float4*)&ald[(size_t)wid * 4];   // wave-uniform

    float m0 = -1e30f, m1 = -1e30f, m2 = -1e30f, m3 = -1e30f;
    for (int i = b + lane; i < e; i += 64) {
        int eid = seid[i];
        int s = ssrc[i];
        float4 as4 = *(const float4*)&als[(size_t)s * 4];
        const float* evp = (eid < EE) ? &ef[(size_t)eid * 6] : &emean[(size_t)wid * 6];
        float ev[6];
#pragma unroll
        for (int k = 0; k < 6; k++) ev[k] = evp[k];
        float o[4] = {as4.x + ad4.x, as4.y + ad4.y, as4.z + ad4.z, as4.w + ad4.w};
#pragma unroll
        for (int h = 0; h < 4; h++) {
#pragma unroll
            for (int k = 0; k < 6; k++) o[h] += ev[k] * Wea[k * 4 + h];
            o[h] = o[h] > 0.f ? o[h] : 0.2f * o[h];
        }
        *(float4*)&al[(size_t)i * 4] = make_float4(o[0], o[1], o[2], o[3]);
        m0 = fmaxf(m0, o[0]); m1 = fmaxf(m1, o[1]);
        m2 = fmaxf(m2, o[2]); m3 = fmaxf(m3, o[3]);
    }
#pragma unroll
    for (int off = 32; off; off >>= 1) {
        m0 = fmaxf(m0, __shfl_xor(m0, off)); m1 = fmaxf(m1, __shfl_xor(m1, off));
        m2 = fmaxf(m2, __shfl_xor(m2, off)); m3 = fmaxf(m3, __shfl_xor(m3, off));
    }
    float s0 = 0.f, s1 = 0.f, s2 = 0.f, s3 = 0.f;
    for (int i = b + lane; i < e; i += 64) {
        float4 v = *(const float4*)&al[(size_t)i * 4];
        s0 += __expf(v.x - m0); s1 += __expf(v.y - m1);
        s2 += __expf(v.z - m2); s3 += __expf(v.w - m3);
    }
#pragma unroll
    for (int off = 32; off; off >>= 1) {
        s0 += __shfl_xor(s0, off); s1 += __shfl_xor(s1, off);
        s2 += __shfl_xor(s2, off); s3 += __shfl_xor(s3, off);
    }
    float r0 = 1.f / (s0 + 1e-16f), r1 = 1.f / (s1 + 1e-16f);
    float r2 = 1.f / (s2 + 1e-16f), r3 = 1.f / (s3 + 1e-16f);
    for (int i = b + lane; i < e; i += 64) {
        float4 v = *(const float4*)&al[(size_t)i * 4];
        v.x = __expf(v.x - m0) * r0;
        v.y = __expf(v.y - m1) * r1;
        v.z = __expf(v.z - m2) * r2;
        v.w = __expf(v.w - m3) * r3;
        *(float4*)&al[(size_t)i * 4] = v;
    }
}

// ----- aggregation + bias + BN + ELU (wave/node, fp8 gather, 8-deep MLP) ----

template <int C_>
__global__ __launch_bounds__(256) void aggregate_kernel(const unsigned char* __restrict__ xs8,
                                                        const float* __restrict__ w,
                                                        const int* __restrict__ rowptr,
                                                        const int* __restrict__ ssrc,
                                                        const float* __restrict__ bias,
                                                        const float* __restrict__ gam,
                                                        const float* __restrict__ bet,
                                                        unsigned short* __restrict__ hout) {
    constexpr int HC = HH * C_;
    constexpr int CPL = HC / 64;   // bytes/lane: 4 (HC=256) or 8 (HC=512)
    int wid = (blockIdx.x * blockDim.x + threadIdx.x) >> 6;
    int lane = threadIdx.x & 63;
    if (wid >= NN) return;
    int b = rowptr[wid], e = rowptr[wid + 1];
    const int h = lane >> 4;
    const int m15 = lane & 15;

    float acc[CPL];
#pragma unroll
    for (int k = 0; k < CPL; k++) acc[k] = 0.f;

    const unsigned char* xbase = xs8 + (size_t)lane * CPL;

    for (int base = b; base < e; base += 64) {
        int cnt = e - base; if (cnt > 64) cnt = 64;
        int spre = (base + lane < e) ? ssrc[base + lane] : wid;
        float wpre[4];
#pragma unroll
        for (int q = 0; q < 4; q++) {
            int idx = base + q * 16 + m15;
            wpre[q] = (idx < e) ? w[(size_t)idx * 4 + h] : 0.f;
        }
        int cnt8 = (cnt + 7) & ~7;
        for (int j = 0; j < cnt8; j += 8) {
            float ww[8];
            if constexpr (CPL == 8) {
                uint2 pk[8];
#pragma unroll
                for (int u = 0; u < 8; u++) {
                    int jj = j + u;
                    int s = __shfl(spre, jj);
                    ww[u] = __shfl(wpre[jj >> 4], (h << 4) | (jj & 15));
                    pk[u] = *(const uint2*)(xbase + (size_t)s * HC);
                }
#pragma unroll
                for (int u = 0; u < 8; u++) {
                    float f[4];
                    dec4_fp8(pk[u].x, f);
                    acc[0] += ww[u] * f[0]; acc[1] += ww[u] * f[1];
                    acc[2] += ww[u] * f[2]; acc[3] += ww[u] * f[3];
                    dec4_fp8(pk[u].y, f);
                    acc[4] += ww[u] * f[0]; acc[5] += ww[u] * f[1];
                    acc[6] += ww[u] * f[2]; acc[7] += ww[u] * f[3];
                }
            } else {
                unsigned int pk[8];
#pragma unroll
                for (int u = 0; u < 8; u++) {
                    int jj = j + u;
                    int s = __shfl(spre, jj);
                    ww[u] = __shfl(wpre[jj >> 4], (h << 4) | (jj & 15));
                    pk[u] = *(const unsigned int*)(xbase + (size_t)s * HC);
                }
#pragma unroll
                for (int u = 0; u < 8; u++) {
                    float f[4];
                    dec4_fp8(pk[u], f);
                    acc[0] += ww[u] * f[0]; acc[1] += ww[u] * f[1];
                    acc[2] += ww[u] * f[2]; acc[3] += ww[u] * f[3];
                }
            }
        }
    }

    int base_c = lane * CPL;
    unsigned int opk[CPL / 2];
#pragma unroll
    for (int q = 0; q < CPL / 4; q++) {
        float4 bi = *(const float4*)&bias[base_c + q * 4];
        float4 ga = *(const float4*)&gam[base_c + q * 4];
        float4 be = *(const float4*)&bet[base_c + q * 4];
        float vv[4];
        vv[0] = ga.x * (acc[q * 4 + 0] + bi.x) * RSQ + be.x;
        vv[1] = ga.y * (acc[q * 4 + 1] + bi.y) * RSQ + be.y;
        vv[2] = ga.z * (acc[q * 4 + 2] + bi.z) * RSQ + be.z;
        vv[3] = ga.w * (acc[q * 4 + 3] + bi.w) * RSQ + be.w;
#pragma unroll
        for (int k = 0; k < 4; k++) vv[k] = vv[k] > 0.f ? vv[k] : (__expf(vv[k]) - 1.0f);
        opk[q * 2 + 0] = (unsigned int)f2bf(vv[0]) | ((unsigned int)f2bf(vv[1]) << 16);
        opk[q * 2 + 1] = (unsigned int)f2bf(vv[2]) | ((unsigned int)f2bf(vv[3]) << 16);
    }
    if constexpr (CPL == 4) {
        *(uint2*)&hout[(size_t)wid * HC + base_c] = make_uint2(opk[0], opk[1]);
    } else {
        *(uint4*)&hout[(size_t)wid * HC + base_c] = make_uint4(opk[0], opk[1], opk[2], opk[3]);
    }
}

// ----------------------------------------------------------- pooling + head

__global__ void bounds_kernel(const int* __restrict__ batch, int* __restrict__ first,
                              int* __restrict__ last) {
    int n = blockIdx.x * blockDim.x + threadIdx.x;
    if (n >= NN) return;
    int b = batch[n];
    if (n == 0 || batch[n - 1] != b) first[b] = n;
    if (n == NN - 1 || batch[n + 1] != b) last[b] = n;
}

// 64 nodes per block (782 blocks) — short serial chain, boundary-flush atomics.
#define PCHUNK 64
__global__ __launch_bounds__(256) void pool_kernel(const unsigned short* __restrict__ h3,
                                                   const int* __restrict__ batch,
                                                   float* __restrict__ pooled) {
    int c = threadIdx.x;
    int n0 = blockIdx.x * PCHUNK;
    int nend = min(n0 + PCHUNK, NN);
    if (n0 >= NN) return;
    float local = 0.f;
    int curg = batch[n0];
    for (int n = n0; n < nend; n++) {
        int g = batch[n];
        if (g != curg) {
            atomicAdd(&pooled[(size_t)curg * 256 + c], local);
            local = 0.f;
            curg = g;
        }
        local += bf2f(h3[(size_t)n * 256 + c]);
    }
    atomicAdd(&pooled[(size_t)curg * 256 + c], local);
}

__global__ void final_kernel(const float* __restrict__ pooled,
                             const int* __restrict__ first, const int* __restrict__ last,
                             const float* __restrict__ Wf1, const float* __restrict__ bf1,
                             const float* __restrict__ gf, const float* __restrict__ bbf,
                             const float* __restrict__ Wf2, const float* __restrict__ bf2,
                             float* __restrict__ out) {
    int g = blockIdx.x;
    int j = threadIdx.x;  // 32 threads
    __shared__ float hh[32];
    float c = fmaxf((float)(last[g] - first[g] + 1), 1.0f);
    float inv = 1.0f / c;
    float acc = bf1[j];
    for (int i = 0; i < 256; i++) acc += (pooled[(size_t)g * 256 + i] * inv) * Wf1[(size_t)i * 32 + j];
    float v = gf[j] * acc * RSQ + bbf[j];
    hh[j] = v > 0.f ? v : (__expf(v) - 1.0f);
    __syncthreads();
    if (j == 0) {
        float l0 = bf2[0], l1 = bf2[1];
        for (int i = 0; i < 32; i++) {
            l0 += hh[i] * Wf2[i * 2 + 0];
            l1 += hh[i] * Wf2[i * 2 + 1];
        }
        float mx = fmaxf(l0, l1);
        float lse = mx + logf(__expf(l0 - mx) + __expf(l1 - mx));
        out[g * 2 + 0] = l0 - lse;
        out[g * 2 + 1] = l1 - lse;
    }
}

// -------------------------------------------------------------------- launch

extern "C" void kernel_launch(void* const* d_in, const int* in_sizes, int n_in,
                              void* d_out, int out_size, void* d_ws, size_t ws_size,
                              hipStream_t stream) {
    (void)in_sizes; (void)n_in; (void)out_size; (void)ws_size;

    const float* x  = (const float*)d_in[0];
    const float* ef = (const float*)d_in[1];
    const float* W_[3]  = {(const float*)d_in[2],  (const float*)d_in[10], (const float*)d_in[18]};
    const float* We_[3] = {(const float*)d_in[3],  (const float*)d_in[11], (const float*)d_in[19]};
    const float* As_[3] = {(const float*)d_in[4],  (const float*)d_in[12], (const float*)d_in[20]};
    const float* Ad_[3] = {(const float*)d_in[5],  (const float*)d_in[13], (const float*)d_in[21]};
    const float* Ae_[3] = {(const float*)d_in[6],  (const float*)d_in[14], (const float*)d_in[22]};
    const float* Bi_[3] = {(const float*)d_in[7],  (const float*)d_in[15], (const float*)d_in[23]};
    const float* Ga_[3] = {(const float*)d_in[8],  (const float*)d_in[16], (const float*)d_in[24]};
    const float* Be_[3] = {(const float*)d_in[9],  (const float*)d_in[17], (const float*)d_in[25]};
    const float* Wf1 = (const float*)d_in[26];
    const float* bf1 = (const float*)d_in[27];
    const float* gf  = (const float*)d_in[28];
    const float* bbf = (const float*)d_in[29];
    const float* Wf2 = (const float*)d_in[30];
    const float* bf2 = (const float*)d_in[31];
    const int* eidx  = (const int*)d_in[32];
    const int* src0  = eidx;
    const int* dst0  = eidx + EE;
    const int* batch = (const int*)d_in[33];
    float* out = (float*)d_out;

    char* p = (char*)d_ws;
    unsigned short* B0 = (unsigned short*)carve(p, (size_t)NPAD * 512 * 2);
    unsigned short* B1 = (unsigned short*)carve(p, (size_t)NPAD * 512 * 2);
    unsigned short* B2 = (unsigned short*)carve(p, (size_t)NPAD * 512 * 2);
    unsigned char*  X8 = (unsigned char*)carve(p, (size_t)NPAD * 512);
    unsigned short* Wt = (unsigned short*)carve(p, (size_t)512 * 512 * 2);
    float* al     = (float*)carve(p, (size_t)ET * 4 * 4);
    float* als    = (float*)carve(p, (size_t)NN * 4 * 4);
    float* ald    = (float*)carve(p, (size_t)NN * 4 * 4);
    float* emean  = (float*)carve(p, (size_t)NN * 6 * 4);
    float* wea    = (float*)carve(p, 256);
    float* pooled = (float*)carve(p, (size_t)GG * 256 * 4);
    int* first  = (int*)carve(p, (size_t)GG * 4);
    int* last   = (int*)carve(p, (size_t)GG * 4);
    int* deg    = (int*)carve(p, (size_t)NN * 4);
    int* rowptr = (int*)carve(p, (size_t)(NN + 1) * 4);
    int* cursor = (int*)carve(p, (size_t)NN * 4);
    int* ssrc   = (int*)carve(p, (size_t)ET * 4);
    int* seid   = (int*)carve(p, (size_t)ET * 4);
    int* bsum   = (int*)carve(p, 512);

    hipMemsetAsync(deg, 0, (size_t)NN * 4, stream);
    hipMemsetAsync(cursor, 0, (size_t)NN * 4, stream);
    hipMemsetAsync(pooled, 0, (size_t)GG * 256 * 4, stream);
    hipMemsetAsync(first, 0x00, (size_t)GG * 4, stream);
    hipMemsetAsync(last, 0xFF, (size_t)GG * 4, stream);

    deg_kernel<<<(EE + 255) / 256, 256, 0, stream>>>(dst0, deg);

    int nb = (NN + SCAN_B - 1) / SCAN_B;  // 98
    scan1_kernel<<<nb, SCAN_B, 0, stream>>>(deg, rowptr, bsum, NN);
    scan2_kernel<<<1, 128, 0, stream>>>(bsum, nb);
    scan3_kernel<<<nb, SCAN_B, 0, stream>>>(rowptr, bsum, NN);
    set_total_kernel<<<1, 64, 0, stream>>>(rowptr);
    fill_edges_kernel<<<(EE + 255) / 256, 256, 0, stream>>>(src0, dst0, rowptr, cursor,
                                                            ssrc, seid);
    fill_loops_kernel<<<(NN + 255) / 256, 256, 0, stream>>>(rowptr, cursor, ssrc, seid);

    int wblocks = (NN * 64 + 255) / 256;
    emean_csr_kernel<<<wblocks, 256, 0, stream>>>(rowptr, seid, ef, emean);

    convx_kernel<<<(NPAD * 32 + 255) / 256, 256, 0, stream>>>(x, B0);

    const int fin[3] = {32, 256, 512};
    const int HCs[3] = {256, 512, 256};
    const int Cs[3]  = {64, 128, 64};
    const unsigned short* inb[3]  = {B0, B2, B0};
    unsigned short* outb[3]       = {B2, B0, B2};

    for (int li = 0; li < 3; li++) {
        int K = fin[li], HC = HCs[li];
        convw_kernel<<<(K * HC + 255) / 256, 256, 0, stream>>>(W_[li], Wt, K, HC);
        dim3 gg(NPAD / 128, HC / 128);
        gemm_bf16_kernel<<<gg, 256, 0, stream>>>(inb[li], Wt, B1, K, HC);

        int total8 = NPAD * HC / 8;
        conv8_kernel<<<(total8 + 255) / 256, 256, 0, stream>>>(B1, (uint2*)X8, total8);

        if (Cs[li] == 64)
            attn_node_kernel<64><<<wblocks, 256, 0, stream>>>(B1, As_[li], Ad_[li], als, ald);
        else
            attn_node_kernel<128><<<wblocks, 256, 0, stream>>>(B1, As_[li], Ad_[li], als, ald);

        wea_kernel<<<1, 32, 0, stream>>>(We_[li], Ae_[li], wea, HC, Cs[li]);
        logits_softmax_kernel<<<wblocks, 256, 0, stream>>>(rowptr, ssrc, seid, ef, emean,
                                                           wea, als, ald, al);

        if (Cs[li] == 64)
            aggregate_kernel<64><<<wblocks, 256, 0, stream>>>(X8, al, rowptr, ssrc,
                                                              Bi_[li], Ga_[li], Be_[li], outb[li]);
        else
            aggregate_kernel<128><<<wblocks, 256, 0, stream>>>(X8, al, rowptr, ssrc,
                                                               Bi_[li], Ga_[li], Be_[li], outb[li]);
    }

    bounds_kernel<<<(NN + 255) / 256, 256, 0, stream>>>(batch, first, last);
    pool_kernel<<<(NN + PCHUNK - 1) / PCHUNK, 256, 0, stream>>>(B2, batch, pooled);
    final_kernel<<<GG, 32, 0, stream>>>(pooled, first, last, Wf1, bf1, gf, bbf, Wf2, bf2, out);
}

// Round 8
// 532.937 us; speedup vs baseline: 1.8210x; 1.1932x over previous
//
#include <hip/hip_runtime.h>
#include <cstdint>
#include <cstddef>

#define NN 50000
#define NPAD 50048            // 391 * 128
#define EE 800000
#define ET (EE + NN)
#define GG 64
#define HH 4
#define RSQ 0.9999950000374997f   // 1/sqrt(1+1e-5)

typedef short bf16x8 __attribute__((ext_vector_type(8)));
typedef unsigned short u16x8 __attribute__((ext_vector_type(8)));
typedef unsigned short u16x4 __attribute__((ext_vector_type(4)));
typedef float f32x4 __attribute__((ext_vector_type(4)));
typedef float f32x2 __attribute__((ext_vector_type(2)));

__device__ __forceinline__ float bf2f(unsigned short u) {
    union { unsigned int i; float f; } v; v.i = ((unsigned int)u) << 16; return v.f;
}
__device__ __forceinline__ unsigned short f2bf(float f) {
    union { float f; unsigned int i; } v; v.f = f;
    unsigned int u = v.i;
    u += 0x7fffu + ((u >> 16) & 1u);
    return (unsigned short)(u >> 16);
}

// ---------------------------------------------------------------- fp8 e4m3

#if __has_builtin(__builtin_amdgcn_cvt_pk_fp8_f32) && __has_builtin(__builtin_amdgcn_cvt_pk_f32_fp8)
#define FP8_HW 1
#else
#define FP8_HW 0
#endif

#if !FP8_HW
__device__ __forceinline__ unsigned int enc1_fp8(float f) {
    unsigned int u = __float_as_uint(f);
    unsigned int s = (u >> 24) & 0x80u;
    float a = fabsf(f);
    a = fminf(a, 448.f);
    unsigned int b;
    if (a >= 0.015625f) {
        unsigned int ub = __float_as_uint(a);
        unsigned int mant = ub & 0x7FFFFFu;
        unsigned int keep = mant >> 20;
        unsigned int rem = mant & 0xFFFFFu;
        unsigned int exp = (ub >> 23) - 127u + 7u;
        unsigned int q = (exp << 3) | keep;
        if (rem > 0x80000u || (rem == 0x80000u && (q & 1u))) q++;
        if (q > 0x7Eu) q = 0x7Eu;
        b = q;
    } else {
        int q = (int)(a * 512.0f + 0.5f);
        b = (q > 7) ? 0x08u : (unsigned int)q;
    }
    return s | b;
}
__device__ __forceinline__ float dec1_fp8(unsigned int b) {
    unsigned int sgn = (b & 0x80u) << 24;
    float r;
    if (b & 0x78u) {
        r = __uint_as_float(sgn | (((b & 0x7Fu) + 0x3C0u) << 20));
    } else {
        r = (float)(b & 7u) * 0x1p-9f;
        r = (b & 0x80u) ? -r : r;
    }
    return r;
}
#endif

__device__ __forceinline__ unsigned int pk4_fp8(float f0, float f1, float f2, float f3) {
#if FP8_HW
    int r = __builtin_amdgcn_cvt_pk_fp8_f32(f0, f1, 0, false);
    r = __builtin_amdgcn_cvt_pk_fp8_f32(f2, f3, r, true);
    return (unsigned int)r;
#else
    return enc1_fp8(f0) | (enc1_fp8(f1) << 8) | (enc1_fp8(f2) << 16) | (enc1_fp8(f3) << 24);
#endif
}

__device__ __forceinline__ f32x2 dec2lo_fp8(unsigned int u) {
#if FP8_HW
    return __builtin_amdgcn_cvt_pk_f32_fp8((int)u, false);
#else
    f32x2 r; r[0] = dec1_fp8(u & 0xFFu); r[1] = dec1_fp8((u >> 8) & 0xFFu); return r;
#endif
}
__device__ __forceinline__ f32x2 dec2hi_fp8(unsigned int u) {
#if FP8_HW
    return __builtin_amdgcn_cvt_pk_f32_fp8((int)u, true);
#else
    f32x2 r; r[0] = dec1_fp8((u >> 16) & 0xFFu); r[1] = dec1_fp8(u >> 24); return r;
#endif
}

static inline void* carve(char*& p, size_t bytes) {
    void* r = (void*)p;
    p += (bytes + 255) & ~(size_t)255;
    return r;
}

// ------------------------------------------------------------- CSR building

__global__ void deg_kernel(const int* __restrict__ dst0, int* __restrict__ deg) {
    int e = blockIdx.x * blockDim.x + threadIdx.x;
    if (e >= EE) return;
    atomicAdd(&deg[dst0[e]], 1);
}

#define SCAN_B 512
__global__ void scan1_kernel(const int* __restrict__ deg, int* __restrict__ out,
                             int* __restrict__ bsum, int n) {
    __shared__ int tmp[SCAN_B];
    int i = blockIdx.x * SCAN_B + threadIdx.x;
    int v = (i < n) ? (deg[i] + 1) : 0;   // +1 self loop
    tmp[threadIdx.x] = v;
    __syncthreads();
    for (int off = 1; off < SCAN_B; off <<= 1) {
        int t = (threadIdx.x >= off) ? tmp[threadIdx.x - off] : 0;
        __syncthreads();
        tmp[threadIdx.x] += t;
        __syncthreads();
    }
    if (i < n) out[i] = tmp[threadIdx.x] - v;       // exclusive
    if (threadIdx.x == SCAN_B - 1) bsum[blockIdx.x] = tmp[threadIdx.x];
}

__global__ void scan2_kernel(int* __restrict__ bsum, int nb) {
    __shared__ int tmp[128];
    int v = (threadIdx.x < nb) ? bsum[threadIdx.x] : 0;
    tmp[threadIdx.x] = v;
    __syncthreads();
    for (int off = 1; off < 128; off <<= 1) {
        int t = (threadIdx.x >= off) ? tmp[threadIdx.x - off] : 0;
        __syncthreads();
        tmp[threadIdx.x] += t;
        __syncthreads();
    }
    if (threadIdx.x < nb) bsum[threadIdx.x] = tmp[threadIdx.x] - v;  // exclusive
}

__global__ void scan3_kernel(int* __restrict__ out, const int* __restrict__ bsum, int n) {
    int i = blockIdx.x * SCAN_B + threadIdx.x;
    if (i < n) out[i] += bsum[blockIdx.x];
}

__global__ void set_total_kernel(int* __restrict__ row_ptr) {
    if (threadIdx.x == 0) row_ptr[NN] = ET;
}

__global__ void fill_edges_kernel(const int* __restrict__ src0, const int* __restrict__ dst0,
                                  const int* __restrict__ row_ptr, int* __restrict__ cursor,
                                  int* __restrict__ ssrc, int* __restrict__ seid) {
    int e = blockIdx.x * blockDim.x + threadIdx.x;
    if (e >= EE) return;
    int d = dst0[e];
    int p = atomicAdd(&cursor[d], 1);
    int idx = row_ptr[d] + p;
    ssrc[idx] = src0[e];
    seid[idx] = e;
}

__global__ void fill_loops_kernel(const int* __restrict__ row_ptr, int* __restrict__ cursor,
                                  int* __restrict__ ssrc, int* __restrict__ seid) {
    int n = blockIdx.x * blockDim.x + threadIdx.x;
    if (n >= NN) return;
    int p = atomicAdd(&cursor[n], 1);
    int idx = row_ptr[n] + p;
    ssrc[idx] = n;
    seid[idx] = EE + n;
}

// emean via CSR segmented sum — no atomics. Wave per node, lanes over edges.
__global__ __launch_bounds__(256) void emean_csr_kernel(const int* __restrict__ rowptr,
                                                        const int* __restrict__ seid,
                                                        const float* __restrict__ ef,
                                                        float* __restrict__ emean) {
    int wid = (blockIdx.x * blockDim.x + threadIdx.x) >> 6;
    int lane = threadIdx.x & 63;
    if (wid >= NN) return;
    int b = rowptr[wid], e = rowptr[wid + 1];
    float s[6] = {0.f, 0.f, 0.f, 0.f, 0.f, 0.f};
    for (int i = b + lane; i < e; i += 64) {
        int eid = seid[i];
        if (eid < EE) {
            const float* row = &ef[(size_t)eid * 6];
#pragma unroll
            for (int k = 0; k < 6; k++) s[k] += row[k];
        }
    }
#pragma unroll
    for (int off = 32; off; off >>= 1)
#pragma unroll
        for (int k = 0; k < 6; k++) s[k] += __shfl_xor(s[k], off);
    if (lane == 0) {
        float inv = 1.0f / fmaxf((float)(e - b - 1), 1.0f);
#pragma unroll
        for (int k = 0; k < 6; k++) emean[(size_t)wid * 6 + k] = s[k] * inv;
    }
}

// ------------------------------------------------------------- conversions

__global__ void convx_kernel(const float* __restrict__ x, unsigned short* __restrict__ xb) {
    int i = blockIdx.x * blockDim.x + threadIdx.x;
    if (i >= NPAD * 32) return;
    int row = i >> 5;
    float v = 0.f;
    if (row < NN) v = x[i];
    xb[i] = f2bf(v);
}

__global__ void convw_kernel(const float* __restrict__ W, unsigned short* __restrict__ Wt,
                             int K, int Nc) {
    int i = blockIdx.x * blockDim.x + threadIdx.x;
    if (i >= K * Nc) return;
    int c = i / K, k = i - c * K;
    Wt[i] = f2bf(W[(size_t)k * Nc + c]);
}

// ------------------------------------------------------------ bf16 MFMA GEMM

__global__ __launch_bounds__(256) void gemm_bf16_kernel(const unsigned short* __restrict__ A,
                                                        const unsigned short* __restrict__ Bt,
                                                        unsigned short* __restrict__ C,
                                                        int K, int Nc) {
    __shared__ unsigned short As[128][40];
    __shared__ unsigned short Bs[128][40];
    const int tid = threadIdx.x;
    const int bm = blockIdx.x * 128;
    const int bn = blockIdx.y * 128;
    const int lane = tid & 63;
    const int wv = tid >> 6;
    const int wrow = (wv >> 1) * 64;
    const int wcol = (wv & 1) * 64;
    const int lrow = tid >> 1;          // 0..127
    const int lseg = (tid & 1) * 16;    // 0 or 16
    const int l15 = lane & 15;
    const int kgrp = (lane >> 4) * 8;

    f32x4 acc[4][4];
#pragma unroll
    for (int m = 0; m < 4; m++)
#pragma unroll
        for (int n = 0; n < 4; n++) acc[m][n] = (f32x4)0.f;

    for (int k0 = 0; k0 < K; k0 += 32) {
        const unsigned short* ga = &A[(size_t)(bm + lrow) * K + k0 + lseg];
        const unsigned short* gb = &Bt[(size_t)(bn + lrow) * K + k0 + lseg];
        u16x8 a0 = *(const u16x8*)ga;
        u16x8 a1 = *(const u16x8*)(ga + 8);
        u16x8 b0 = *(const u16x8*)gb;
        u16x8 b1 = *(const u16x8*)(gb + 8);
        *(u16x8*)&As[lrow][lseg] = a0;
        *(u16x8*)&As[lrow][lseg + 8] = a1;
        *(u16x8*)&Bs[lrow][lseg] = b0;
        *(u16x8*)&Bs[lrow][lseg + 8] = b1;
        __syncthreads();
        bf16x8 af[4], bfr[4];
#pragma unroll
        for (int m = 0; m < 4; m++)
            af[m] = *(const bf16x8*)&As[wrow + m * 16 + l15][kgrp];
#pragma unroll
        for (int n = 0; n < 4; n++)
            bfr[n] = *(const bf16x8*)&Bs[wcol + n * 16 + l15][kgrp];
#pragma unroll
        for (int m = 0; m < 4; m++)
#pragma unroll
            for (int n = 0; n < 4; n++)
                acc[m][n] = __builtin_amdgcn_mfma_f32_16x16x32_bf16(af[m], bfr[n], acc[m][n], 0, 0, 0);
        __syncthreads();
    }
#pragma unroll
    for (int m = 0; m < 4; m++) {
#pragma unroll
        for (int n = 0; n < 4; n++) {
#pragma unroll
            for (int j = 0; j < 4; j++) {
                int row = bm + wrow + m * 16 + (lane >> 4) * 4 + j;
                int col = bn + wcol + n * 16 + l15;
                C[(size_t)row * Nc + col] = f2bf(acc[m][n][j]);
            }
        }
    }
}

// ------ fused post-GEMM: bf16 -> fp8 mirror + attention dots (wave/node) ----
// lane owns CPL contiguous channels, all within head h = lane>>4.

template <int C_>
__global__ __launch_bounds__(256) void post_kernel(const unsigned short* __restrict__ B1,
                                                   unsigned char* __restrict__ X8,
                                                   const float* __restrict__ a_s,
                                                   const float* __restrict__ a_d,
                                                   float* __restrict__ als,
                                                   float* __restrict__ ald) {
    constexpr int HC = HH * C_;
    constexpr int CPL = HC / 64;   // 4 or 8
    int wid = (blockIdx.x * blockDim.x + threadIdx.x) >> 6;
    int lane = threadIdx.x & 63;
    if (wid >= NN) return;
    int base = lane * CPL;
    const unsigned short* row = B1 + (size_t)wid * HC + base;

    float f[CPL];
    if constexpr (CPL == 8) {
        u16x8 v = *(const u16x8*)row;
#pragma unroll
        for (int k = 0; k < 8; k++) f[k] = bf2f(v[k]);
    } else {
        u16x4 v = *(const u16x4*)row;
#pragma unroll
        for (int k = 0; k < 4; k++) f[k] = bf2f(v[k]);
    }

    // fp8 mirror
    unsigned int r0 = pk4_fp8(f[0], f[1], f[2], f[3]);
    if constexpr (CPL == 8) {
        unsigned int r1 = pk4_fp8(f[4], f[5], f[6], f[7]);
        *(uint2*)&X8[(size_t)wid * HC + base] = make_uint2(r0, r1);
    } else {
        *(unsigned int*)&X8[(size_t)wid * HC + base] = r0;
    }

    // attention dots (within-head partial, 16-lane reduce)
    float ps = 0.f, pd = 0.f;
#pragma unroll
    for (int k = 0; k < CPL; k++) {
        ps += f[k] * a_s[base + k];
        pd += f[k] * a_d[base + k];
    }
#pragma unroll
    for (int off = 8; off; off >>= 1) {
        ps += __shfl_xor(ps, off);
        pd += __shfl_xor(pd, off);
    }
    if ((lane & 15) == 0) {
        int h = lane >> 4;
        als[(size_t)wid * HH + h] = ps;
        ald[(size_t)wid * HH + h] = pd;
    }
}

// ------------------------------------------------------------- edge logits

__global__ void wea_kernel(const float* __restrict__ We, const float* __restrict__ ae,
                           float* __restrict__ Wea, int HC, int C) {
    int t = threadIdx.x;
    if (t >= 24) return;
    int k = t / 4, h = t % 4;
    float s = 0.f;
    for (int c = 0; c < C; c++) s += We[(size_t)k * HC + h * C + c] * ae[(size_t)h * C + c];
    Wea[k * 4 + h] = s;
}

// -------- fused: CSR-ordered edge logits + leaky-relu + per-dst softmax -----

__global__ __launch_bounds__(256) void logits_softmax_kernel(
        const int* __restrict__ rowptr, const int* __restrict__ ssrc,
        const int* __restrict__ seid, const float* __restrict__ ef,
        const float* __restrict__ emean, const float* __restrict__ Wea,
        const float* __restrict__ als, const float* __restrict__ ald,
        float* __restrict__ al) {
    int wid = (blockIdx.x * blockDim.x + threadIdx.x) >> 6;
    int lane = threadIdx.x & 63;
    if (wid >= NN) return;
    int b = rowptr[wid], e = rowptr[wid + 1];
    float4 ad4 = *(const float4*)&ald[(size_t)wid * 4];   // wave-uniform

    float m0 = -1e30f, m1 = -1e30f, m2 = -1e30f, m3 = -1e30f;
    for (int i = b + lane; i < e; i += 64) {
        int eid = seid[i];
        int s = ssrc[i];
        float4 as4 = *(const float4*)&als[(size_t)s * 4];
        const float* evp = (eid < EE) ? &ef[(size_t)eid * 6] : &emean[(size_t)wid * 6];
        float ev[6];
#pragma unroll
        for (int k = 0; k < 6; k++) ev[k] = evp[k];
        float o[4] = {as4.x + ad4.x, as4.y + ad4.y, as4.z + ad4.z, as4.w + ad4.w};
#pragma unroll
        for (int h = 0; h < 4; h++) {
#pragma unroll
            for (int k = 0; k < 6; k++) o[h] += ev[k] * Wea[k * 4 + h];
            o[h] = o[h] > 0.f ? o[h] : 0.2f * o[h];
        }
        *(float4*)&al[(size_t)i * 4] = make_float4(o[0], o[1], o[2], o[3]);
        m0 = fmaxf(m0, o[0]); m1 = fmaxf(m1, o[1]);
        m2 = fmaxf(m2, o[2]); m3 = fmaxf(m3, o[3]);
    }
#pragma unroll
    for (int off = 32; off; off >>= 1) {
        m0 = fmaxf(m0, __shfl_xor(m0, off)); m1 = fmaxf(m1, __shfl_xor(m1, off));
        m2 = fmaxf(m2, __shfl_xor(m2, off)); m3 = fmaxf(m3, __shfl_xor(m3, off));
    }
    float s0 = 0.f, s1 = 0.f, s2 = 0.f, s3 = 0.f;
    for (int i = b + lane; i < e; i += 64) {
        float4 v = *(const float4*)&al[(size_t)i * 4];
        s0 += __expf(v.x - m0); s1 += __expf(v.y - m1);
        s2 += __expf(v.z - m2); s3 += __expf(v.w - m3);
    }
#pragma unroll
    for (int off = 32; off; off >>= 1) {
        s0 += __shfl_xor(s0, off); s1 += __shfl_xor(s1, off);
        s2 += __shfl_xor(s2, off); s3 += __shfl_xor(s3, off);
    }
    float r0 = 1.f / (s0 + 1e-16f), r1 = 1.f / (s1 + 1e-16f);
    float r2 = 1.f / (s2 + 1e-16f), r3 = 1.f / (s3 + 1e-16f);
    for (int i = b + lane; i < e; i += 64) {
        float4 v = *(const float4*)&al[(size_t)i * 4];
        v.x = __expf(v.x - m0) * r0;
        v.y = __expf(v.y - m1) * r1;
        v.z = __expf(v.z - m2) * r2;
        v.w = __expf(v.w - m3) * r3;
        *(float4*)&al[(size_t)i * 4] = v;
    }
}

// --- aggregation + bias + BN + ELU (wave/node, fp8 gather, packed f32x2 FMA)

template <int C_>
__global__ __launch_bounds__(256) void aggregate_kernel(const unsigned char* __restrict__ xs8,
                                                        const float* __restrict__ w,
                                                        const int* __restrict__ rowptr,
                                                        const int* __restrict__ ssrc,
                                                        const float* __restrict__ bias,
                                                        const float* __restrict__ gam,
                                                        const float* __restrict__ bet,
                                                        unsigned short* __restrict__ hout) {
    constexpr int HC = HH * C_;
    constexpr int CPL = HC / 64;   // bytes/lane: 4 (HC=256) or 8 (HC=512)
    int wid = (blockIdx.x * blockDim.x + threadIdx.x) >> 6;
    int lane = threadIdx.x & 63;
    if (wid >= NN) return;
    int b = rowptr[wid], e = rowptr[wid + 1];
    const int h = lane >> 4;
    const int m15 = lane & 15;

    f32x2 acc2[CPL / 2];
#pragma unroll
    for (int k = 0; k < CPL / 2; k++) acc2[k] = (f32x2)0.f;

    const unsigned char* xbase = xs8 + (size_t)lane * CPL;

    for (int base = b; base < e; base += 64) {
        int cnt = e - base; if (cnt > 64) cnt = 64;
        int spre = (base + lane < e) ? ssrc[base + lane] : wid;
        float wpre[4];
#pragma unroll
        for (int q = 0; q < 4; q++) {
            int idx = base + q * 16 + m15;
            wpre[q] = (idx < e) ? w[(size_t)idx * 4 + h] : 0.f;
        }
        int cnt8 = (cnt + 7) & ~7;
        for (int j = 0; j < cnt8; j += 8) {
            if constexpr (CPL == 8) {
                uint2 pk[8];
                float ww[8];
#pragma unroll
                for (int u = 0; u < 8; u++) {
                    int jj = j + u;
                    int s = __shfl(spre, jj);
                    ww[u] = __shfl(wpre[jj >> 4], (h << 4) | (jj & 15));
                    pk[u] = *(const uint2*)(xbase + (size_t)s * HC);
                }
#pragma unroll
                for (int u = 0; u < 8; u++) {
                    f32x2 wv; wv[0] = ww[u]; wv[1] = ww[u];
                    acc2[0] += wv * dec2lo_fp8(pk[u].x);
                    acc2[1] += wv * dec2hi_fp8(pk[u].x);
                    acc2[2] += wv * dec2lo_fp8(pk[u].y);
                    acc2[3] += wv * dec2hi_fp8(pk[u].y);
                }
            } else {
                unsigned int pk[8];
                float ww[8];
#pragma unroll
                for (int u = 0; u < 8; u++) {
                    int jj = j + u;
                    int s = __shfl(spre, jj);
                    ww[u] = __shfl(wpre[jj >> 4], (h << 4) | (jj & 15));
                    pk[u] = *(const unsigned int*)(xbase + (size_t)s * HC);
                }
#pragma unroll
                for (int u = 0; u < 8; u++) {
                    f32x2 wv; wv[0] = ww[u]; wv[1] = ww[u];
                    acc2[0] += wv * dec2lo_fp8(pk[u]);
                    acc2[1] += wv * dec2hi_fp8(pk[u]);
                }
            }
        }
    }

    float acc[CPL];
#pragma unroll
    for (int k = 0; k < CPL / 2; k++) { acc[2 * k] = acc2[k][0]; acc[2 * k + 1] = acc2[k][1]; }

    int base_c = lane * CPL;
    unsigned int opk[CPL / 2];
#pragma unroll
    for (int q = 0; q < CPL / 4; q++) {
        float4 bi = *(const float4*)&bias[base_c + q * 4];
        float4 ga = *(const float4*)&gam[base_c + q * 4];
        float4 be = *(const float4*)&bet[base_c + q * 4];
        float vv[4];
        vv[0] = ga.x * (acc[q * 4 + 0] + bi.x) * RSQ + be.x;
        vv[1] = ga.y * (acc[q * 4 + 1] + bi.y) * RSQ + be.y;
        vv[2] = ga.z * (acc[q * 4 + 2] + bi.z) * RSQ + be.z;
        vv[3] = ga.w * (acc[q * 4 + 3] + bi.w) * RSQ + be.w;
#pragma unroll
        for (int k = 0; k < 4; k++) vv[k] = vv[k] > 0.f ? vv[k] : (__expf(vv[k]) - 1.0f);
        opk[q * 2 + 0] = (unsigned int)f2bf(vv[0]) | ((unsigned int)f2bf(vv[1]) << 16);
        opk[q * 2 + 1] = (unsigned int)f2bf(vv[2]) | ((unsigned int)f2bf(vv[3]) << 16);
    }
    if constexpr (CPL == 4) {
        *(uint2*)&hout[(size_t)wid * HC + base_c] = make_uint2(opk[0], opk[1]);
    } else {
        *(uint4*)&hout[(size_t)wid * HC + base_c] = make_uint4(opk[0], opk[1], opk[2], opk[3]);
    }
}

// ----------------------------------------------------------- pooling + head

__global__ void bounds_kernel(const int* __restrict__ batch, int* __restrict__ first,
                              int* __restrict__ last) {
    int n = blockIdx.x * blockDim.x + threadIdx.x;
    if (n >= NN) return;
    int b = batch[n];
    if (n == 0 || batch[n - 1] != b) first[b] = n;
    if (n == NN - 1 || batch[n + 1] != b) last[b] = n;
}

#define PCHUNK 64
__global__ __launch_bounds__(256) void pool_kernel(const unsigned short* __restrict__ h3,
                                                   const int* __restrict__ batch,
                                                   float* __restrict__ pooled) {
    int c = threadIdx.x;
    int n0 = blockIdx.x * PCHUNK;
    int nend = min(n0 + PCHUNK, NN);
    if (n0 >= NN) return;
    float local = 0.f;
    int curg = batch[n0];
    for (int n = n0; n < nend; n++) {
        int g = batch[n];
        if (g != curg) {
            atomicAdd(&pooled[(size_t)curg * 256 + c], local);
            local = 0.f;
            curg = g;
        }
        local += bf2f(h3[(size_t)n * 256 + c]);
    }
    atomicAdd(&pooled[(size_t)curg * 256 + c], local);
}

__global__ void final_kernel(const float* __restrict__ pooled,
                             const int* __restrict__ first, const int* __restrict__ last,
                             const float* __restrict__ Wf1, const float* __restrict__ bf1,
                             const float* __restrict__ gf, const float* __restrict__ bbf,
                             const float* __restrict__ Wf2, const float* __restrict__ bf2,
                             float* __restrict__ out) {
    int g = blockIdx.x;
    int j = threadIdx.x;  // 32 threads
    __shared__ float hh[32];
    float c = fmaxf((float)(last[g] - first[g] + 1), 1.0f);
    float inv = 1.0f / c;
    float acc = bf1[j];
    for (int i = 0; i < 256; i++) acc += (pooled[(size_t)g * 256 + i] * inv) * Wf1[(size_t)i * 32 + j];
    float v = gf[j] * acc * RSQ + bbf[j];
    hh[j] = v > 0.f ? v : (__expf(v) - 1.0f);
    __syncthreads();
    if (j == 0) {
        float l0 = bf2[0], l1 = bf2[1];
        for (int i = 0; i < 32; i++) {
            l0 += hh[i] * Wf2[i * 2 + 0];
            l1 += hh[i] * Wf2[i * 2 + 1];
        }
        float mx = fmaxf(l0, l1);
        float lse = mx + logf(__expf(l0 - mx) + __expf(l1 - mx));
        out[g * 2 + 0] = l0 - lse;
        out[g * 2 + 1] = l1 - lse;
    }
}

// -------------------------------------------------------------------- launch

extern "C" void kernel_launch(void* const* d_in, const int* in_sizes, int n_in,
                              void* d_out, int out_size, void* d_ws, size_t ws_size,
                              hipStream_t stream) {
    (void)in_sizes; (void)n_in; (void)out_size; (void)ws_size;

    const float* x  = (const float*)d_in[0];
    const float* ef = (const float*)d_in[1];
    const float* W_[3]  = {(const float*)d_in[2],  (const float*)d_in[10], (const float*)d_in[18]};
    const float* We_[3] = {(const float*)d_in[3],  (const float*)d_in[11], (const float*)d_in[19]};
    const float* As_[3] = {(const float*)d_in[4],  (const float*)d_in[12], (const float*)d_in[20]};
    const float* Ad_[3] = {(const float*)d_in[5],  (const float*)d_in[13], (const float*)d_in[21]};
    const float* Ae_[3] = {(const float*)d_in[6],  (const float*)d_in[14], (const float*)d_in[22]};
    const float* Bi_[3] = {(const float*)d_in[7],  (const float*)d_in[15], (const float*)d_in[23]};
    const float* Ga_[3] = {(const float*)d_in[8],  (const float*)d_in[16], (const float*)d_in[24]};
    const float* Be_[3] = {(const float*)d_in[9],  (const float*)d_in[17], (const float*)d_in[25]};
    const float* Wf1 = (const float*)d_in[26];
    const float* bf1 = (const float*)d_in[27];
    const float* gf  = (const float*)d_in[28];
    const float* bbf = (const float*)d_in[29];
    const float* Wf2 = (const float*)d_in[30];
    const float* bf2 = (const float*)d_in[31];
    const int* eidx  = (const int*)d_in[32];
    const int* src0  = eidx;
    const int* dst0  = eidx + EE;
    const int* batch = (const int*)d_in[33];
    float* out = (float*)d_out;

    char* p = (char*)d_ws;
    unsigned short* B0 = (unsigned short*)carve(p, (size_t)NPAD * 512 * 2);
    unsigned short* B1 = (unsigned short*)carve(p, (size_t)NPAD * 512 * 2);
    unsigned short* B2 = (unsigned short*)carve(p, (size_t)NPAD * 512 * 2);
    unsigned char*  X8 = (unsigned char*)carve(p, (size_t)NPAD * 512);
    unsigned short* Wt = (unsigned short*)carve(p, (size_t)512 * 512 * 2);
    float* al     = (float*)carve(p, (size_t)ET * 4 * 4);
    float* als    = (float*)carve(p, (size_t)NN * 4 * 4);
    float* ald    = (float*)carve(p, (size_t)NN * 4 * 4);
    float* emean  = (float*)carve(p, (size_t)NN * 6 * 4);
    float* wea    = (float*)carve(p, 256);
    float* pooled = (float*)carve(p, (size_t)GG * 256 * 4);
    int* first  = (int*)carve(p, (size_t)GG * 4);
    int* last   = (int*)carve(p, (size_t)GG * 4);
    int* deg    = (int*)carve(p, (size_t)NN * 4);
    int* rowptr = (int*)carve(p, (size_t)(NN + 1) * 4);
    int* cursor = (int*)carve(p, (size_t)NN * 4);
    int* ssrc   = (int*)carve(p, (size_t)ET * 4);
    int* seid   = (int*)carve(p, (size_t)ET * 4);
    int* bsum   = (int*)carve(p, 512);

    hipMemsetAsync(deg, 0, (size_t)NN * 4, stream);
    hipMemsetAsync(cursor, 0, (size_t)NN * 4, stream);
    hipMemsetAsync(pooled, 0, (size_t)GG * 256 * 4, stream);
    hipMemsetAsync(first, 0x00, (size_t)GG * 4, stream);
    hipMemsetAsync(last, 0xFF, (size_t)GG * 4, stream);

    deg_kernel<<<(EE + 255) / 256, 256, 0, stream>>>(dst0, deg);

    int nb = (NN + SCAN_B - 1) / SCAN_B;  // 98
    scan1_kernel<<<nb, SCAN_B, 0, stream>>>(deg, rowptr, bsum, NN);
    scan2_kernel<<<1, 128, 0, stream>>>(bsum, nb);
    scan3_kernel<<<nb, SCAN_B, 0, stream>>>(rowptr, bsum, NN);
    set_total_kernel<<<1, 64, 0, stream>>>(rowptr);
    fill_edges_kernel<<<(EE + 255) / 256, 256, 0, stream>>>(src0, dst0, rowptr, cursor,
                                                            ssrc, seid);
    fill_loops_kernel<<<(NN + 255) / 256, 256, 0, stream>>>(rowptr, cursor, ssrc, seid);

    int wblocks = (NN * 64 + 255) / 256;
    emean_csr_kernel<<<wblocks, 256, 0, stream>>>(rowptr, seid, ef, emean);

    convx_kernel<<<(NPAD * 32 + 255) / 256, 256, 0, stream>>>(x, B0);

    const int fin[3] = {32, 256, 512};
    const int HCs[3] = {256, 512, 256};
    const int Cs[3]  = {64, 128, 64};
    const unsigned short* inb[3]  = {B0, B2, B0};
    unsigned short* outb[3]       = {B2, B0, B2};

    for (int li = 0; li < 3; li++) {
        int K = fin[li], HC = HCs[li];
        convw_kernel<<<(K * HC + 255) / 256, 256, 0, stream>>>(W_[li], Wt, K, HC);
        dim3 gg(NPAD / 128, HC / 128);
        gemm_bf16_kernel<<<gg, 256, 0, stream>>>(inb[li], Wt, B1, K, HC);

        if (Cs[li] == 64)
            post_kernel<64><<<wblocks, 256, 0, stream>>>(B1, X8, As_[li], Ad_[li], als, ald);
        else
            post_kernel<128><<<wblocks, 256, 0, stream>>>(B1, X8, As_[li], Ad_[li], als, ald);

        wea_kernel<<<1, 32, 0, stream>>>(We_[li], Ae_[li], wea, HC, Cs[li]);
        logits_softmax_kernel<<<wblocks, 256, 0, stream>>>(rowptr, ssrc, seid, ef, emean,
                                                           wea, als, ald, al);

        if (Cs[li] == 64)
            aggregate_kernel<64><<<wblocks, 256, 0, stream>>>(X8, al, rowptr, ssrc,
                                                              Bi_[li], Ga_[li], Be_[li], outb[li]);
        else
            aggregate_kernel<128><<<wblocks, 256, 0, stream>>>(X8, al, rowptr, ssrc,
                                                               Bi_[li], Ga_[li], Be_[li], outb[li]);
    }

    bounds_kernel<<<(NN + 255) / 256, 256, 0, stream>>>(batch, first, last);
    pool_kernel<<<(NN + PCHUNK - 1) / PCHUNK, 256, 0, stream>>>(B2, batch, pooled);
    final_kernel<<<GG, 32, 0, stream>>>(pooled, first, last, Wf1, bf1, gf, bbf, Wf2, bf2, out);
}